// Round 1
// baseline (906.745 us; speedup 1.0000x reference)
//
#include <hip/hip_runtime.h>
#include <math.h>

#define N_NODES 40000
#define N_EDGES 640000
#define IN_F 256
#define H_F 128
#define C_F 64
#define L_LAYERS 4

// ---------------- degree count ----------------
__global__ void deg_kernel(const int* __restrict__ src, const int* __restrict__ dst,
                           int* __restrict__ deg_out, int* __restrict__ deg_in) {
    int e = blockIdx.x * blockDim.x + threadIdx.x;
    if (e >= N_EDGES) return;
    atomicAdd(&deg_out[src[e]], 1);
    atomicAdd(&deg_in[dst[e]], 1);
}

// ---------------- exclusive prefix sum over deg_in -> row_ptr ----------------
__global__ void scan_kernel(const int* __restrict__ deg, int* __restrict__ row_ptr) {
    __shared__ int wsum[16];
    int tid = threadIdx.x;
    int lane = tid & 63, wid = tid >> 6;
    int carry = 0;
    for (int base = 0; base < N_NODES; base += 1024) {
        int i = base + tid;
        int v = (i < N_NODES) ? deg[i] : 0;
        int incl = v;
        #pragma unroll
        for (int off = 1; off < 64; off <<= 1) {
            int t = __shfl_up(incl, off, 64);
            if (lane >= off) incl += t;
        }
        if (lane == 63) wsum[wid] = incl;
        __syncthreads();
        int prefix = 0, total = 0;
        #pragma unroll
        for (int w = 0; w < 16; w++) {
            int s = wsum[w];
            if (w < wid) prefix += s;
            total += s;
        }
        if (i < N_NODES) row_ptr[i + 1] = carry + prefix + incl;
        carry += total;
        __syncthreads();   // protect wsum before next chunk's write
    }
    if (tid == 0) row_ptr[0] = 0;
}

// ---------------- CSR fill (by dst) with premultiplied symmetric norm ----------------
__global__ void fill_csr(const int* __restrict__ src, const int* __restrict__ dst,
                         const int* __restrict__ row_ptr, int* __restrict__ cursor,
                         const int* __restrict__ deg_out, const int* __restrict__ deg_in,
                         int* __restrict__ col, float* __restrict__ wv) {
    int e = blockIdx.x * blockDim.x + threadIdx.x;
    if (e >= N_EDGES) return;
    int s = src[e], d = dst[e];
    int pos = row_ptr[d] + atomicAdd(&cursor[d], 1);
    int ds = deg_out[s]; if (ds < 1) ds = 1;
    int dd = deg_in[d];  if (dd < 1) dd = 1;
    col[pos] = s;
    wv[pos] = (1.0f / sqrtf((float)ds)) * (1.0f / sqrtf((float)dd));
}

// ---------------- fc1: h0 = relu(x @ fc1_w + b), [N,256]x[256,128] ----------------
__global__ __launch_bounds__(128) void fc1_kernel(const float* __restrict__ x,
                                                  const float* __restrict__ w,
                                                  const float* __restrict__ b,
                                                  float* __restrict__ h0) {
    __shared__ float sx[8 * IN_F];
    int j = threadIdx.x;           // output column 0..127
    int row0 = blockIdx.x * 8;
    const float* xblk = x + (size_t)row0 * IN_F;
    for (int i = j; i < 8 * IN_F; i += 128) sx[i] = xblk[i];
    __syncthreads();
    float acc[8] = {};
    #pragma unroll 4
    for (int k = 0; k < IN_F; k++) {
        float wvl = w[k * H_F + j];
        #pragma unroll
        for (int r = 0; r < 8; r++) acc[r] += sx[r * IN_F + k] * wvl;
    }
    float bj = b[j];
    #pragma unroll
    for (int r = 0; r < 8; r++) {
        float v = acc[r] + bj;
        h0[(size_t)(row0 + r) * H_F + j] = v > 0.f ? v : 0.f;
    }
}

// ---------------- SpMM: agg[n] = sum_e wv[e] * h[col[e]]  (norms folded into wv) ----
__global__ __launch_bounds__(128) void spmm_kernel(const float* __restrict__ h,
                                                   const int* __restrict__ row_ptr,
                                                   const int* __restrict__ col,
                                                   const float* __restrict__ wv,
                                                   float* __restrict__ agg) {
    int n = blockIdx.x;
    int j = threadIdx.x;
    int e0 = row_ptr[n], e1 = row_ptr[n + 1];
    float acc = 0.f;
    for (int e = e0; e < e1; e++) {
        int c = col[e];           // uniform across block
        float wgt = wv[e];
        acc += wgt * h[(size_t)c * H_F + j];
    }
    agg[(size_t)n * H_F + j] = acc;
}

// ---------------- combine: h_out = relu((1-b)(feat+f0) + b(feat@W1 + f0@W2) + bgc + h_in)
__global__ __launch_bounds__(128) void combine_kernel(const float* __restrict__ agg,
                                                      const float* __restrict__ h0,
                                                      const float* __restrict__ h_in,
                                                      const float* __restrict__ W1,
                                                      const float* __restrict__ W2,
                                                      const float* __restrict__ bgc,
                                                      float beta,
                                                      float* __restrict__ h_out) {
    __shared__ float sfeat[8 * H_F];
    __shared__ float sf0[8 * H_F];
    int j = threadIdx.x;
    int row0 = blockIdx.x * 8;
    size_t base = (size_t)row0 * H_F;
    for (int i = j; i < 8 * H_F; i += 128) {
        sfeat[i] = 0.5f * agg[base + i];   // feat = (1-ALPHA)*agg, ALPHA=0.5
        sf0[i]   = 0.5f * h0[base + i];    // f0   = ALPHA*h0
    }
    __syncthreads();
    float acc[8] = {};
    #pragma unroll 2
    for (int k = 0; k < H_F; k++) {
        float w1 = W1[k * H_F + j];
        float w2 = W2[k * H_F + j];
        #pragma unroll
        for (int r = 0; r < 8; r++)
            acc[r] += sfeat[r * H_F + k] * w1 + sf0[r * H_F + k] * w2;
    }
    float bj = bgc[j];
    float omb = 1.f - beta;
    #pragma unroll
    for (int r = 0; r < 8; r++) {
        int idx = r * H_F + j;
        float rst = omb * (sfeat[idx] + sf0[idx]) + beta * acc[r] + bj;
        float v = rst + h_in[base + idx];
        h_out[base + idx] = v > 0.f ? v : 0.f;
    }
}

// ---------------- fc2: out = h @ fc2_w + b, [N,128]x[128,64] ----------------
__global__ __launch_bounds__(64) void fc2_kernel(const float* __restrict__ h,
                                                 const float* __restrict__ w,
                                                 const float* __restrict__ b,
                                                 float* __restrict__ out) {
    __shared__ float sh[8 * H_F];
    int j = threadIdx.x;           // 0..63
    int row0 = blockIdx.x * 8;
    size_t base = (size_t)row0 * H_F;
    for (int i = j; i < 8 * H_F; i += 64) sh[i] = h[base + i];
    __syncthreads();
    float acc[8] = {};
    #pragma unroll 2
    for (int k = 0; k < H_F; k++) {
        float wvl = w[k * C_F + j];
        #pragma unroll
        for (int r = 0; r < 8; r++) acc[r] += sh[r * H_F + k] * wvl;
    }
    float bj = b[j];
    #pragma unroll
    for (int r = 0; r < 8; r++)
        out[(size_t)(row0 + r) * C_F + j] = acc[r] + bj;
}

extern "C" void kernel_launch(void* const* d_in, const int* in_sizes, int n_in,
                              void* d_out, int out_size, void* d_ws, size_t ws_size,
                              hipStream_t stream) {
    const float* x     = (const float*)d_in[0];
    const float* fc1_w = (const float*)d_in[1];
    const float* fc1_b = (const float*)d_in[2];
    const float* W1    = (const float*)d_in[3];
    const float* W2    = (const float*)d_in[4];
    const float* bgc   = (const float*)d_in[5];
    const float* fc2_w = (const float*)d_in[6];
    const float* fc2_b = (const float*)d_in[7];
    const int*   src   = (const int*)d_in[8];
    const int*   dst   = (const int*)d_in[9];
    float* out = (float*)d_out;

    char* p = (char*)d_ws;
    auto alloc = [&](size_t bytes) {
        char* r = p;
        p += (bytes + 255) & ~(size_t)255;
        return r;
    };
    int*   deg_out = (int*)alloc((size_t)N_NODES * 4);
    int*   deg_in  = (int*)alloc((size_t)N_NODES * 4);
    int*   row_ptr = (int*)alloc((size_t)(N_NODES + 1) * 4);
    int*   cursor  = (int*)alloc((size_t)N_NODES * 4);
    int*   col     = (int*)alloc((size_t)N_EDGES * 4);
    float* wv      = (float*)alloc((size_t)N_EDGES * 4);
    float* h0      = (float*)alloc((size_t)N_NODES * H_F * 4);
    float* hA      = (float*)alloc((size_t)N_NODES * H_F * 4);
    float* hB      = (float*)alloc((size_t)N_NODES * H_F * 4);
    float* agg     = (float*)alloc((size_t)N_NODES * H_F * 4);

    hipMemsetAsync(deg_out, 0, (size_t)N_NODES * 4, stream);
    hipMemsetAsync(deg_in,  0, (size_t)N_NODES * 4, stream);
    hipMemsetAsync(cursor,  0, (size_t)N_NODES * 4, stream);

    deg_kernel<<<(N_EDGES + 255) / 256, 256, 0, stream>>>(src, dst, deg_out, deg_in);
    scan_kernel<<<1, 1024, 0, stream>>>(deg_in, row_ptr);
    fill_csr<<<(N_EDGES + 255) / 256, 256, 0, stream>>>(src, dst, row_ptr, cursor,
                                                        deg_out, deg_in, col, wv);
    fc1_kernel<<<N_NODES / 8, 128, 0, stream>>>(x, fc1_w, fc1_b, h0);

    const float* h_in = h0;
    float* bufs[2] = {hA, hB};
    for (int l = 0; l < L_LAYERS; l++) {
        float beta = (float)log(1.0 / (double)(l + 1) + 1.0);
        float* h_out = bufs[l & 1];
        spmm_kernel<<<N_NODES, 128, 0, stream>>>(h_in, row_ptr, col, wv, agg);
        combine_kernel<<<N_NODES / 8, 128, 0, stream>>>(agg, h0, h_in,
                                                        W1 + (size_t)l * H_F * H_F,
                                                        W2 + (size_t)l * H_F * H_F,
                                                        bgc + (size_t)l * H_F,
                                                        beta, h_out);
        h_in = h_out;
    }
    fc2_kernel<<<N_NODES / 8, 64, 0, stream>>>(h_in, fc2_w, fc2_b, out);
}

// Round 2
// 677.035 us; speedup vs baseline: 1.3393x; 1.3393x over previous
//
#include <hip/hip_runtime.h>
#include <math.h>

#define N_NODES 40000
#define N_EDGES 640000
#define IN_F 256
#define H_F 128
#define C_F 64
#define L_LAYERS 4

typedef short short8 __attribute__((ext_vector_type(8)));
typedef float f32x4 __attribute__((ext_vector_type(4)));

__device__ inline short to_bf16(float f) {
    unsigned u = __builtin_bit_cast(unsigned, f);
    unsigned r = (u + 0x7FFFu + ((u >> 16) & 1u)) >> 16;
    return (short)r;
}

// ---------------- degree count ----------------
__global__ void deg_kernel(const int* __restrict__ src, const int* __restrict__ dst,
                           int* __restrict__ deg_out, int* __restrict__ deg_in) {
    int e = blockIdx.x * blockDim.x + threadIdx.x;
    if (e >= N_EDGES) return;
    atomicAdd(&deg_out[src[e]], 1);
    atomicAdd(&deg_in[dst[e]], 1);
}

// ---------------- exclusive prefix sum over deg_in -> row_ptr ----------------
__global__ void scan_kernel(const int* __restrict__ deg, int* __restrict__ row_ptr) {
    __shared__ int wsum[16];
    int tid = threadIdx.x;
    int lane = tid & 63, wid = tid >> 6;
    int carry = 0;
    for (int base = 0; base < N_NODES; base += 1024) {
        int i = base + tid;
        int v = (i < N_NODES) ? deg[i] : 0;
        int incl = v;
        #pragma unroll
        for (int off = 1; off < 64; off <<= 1) {
            int t = __shfl_up(incl, off, 64);
            if (lane >= off) incl += t;
        }
        if (lane == 63) wsum[wid] = incl;
        __syncthreads();
        int prefix = 0, total = 0;
        #pragma unroll
        for (int w = 0; w < 16; w++) {
            int s = wsum[w];
            if (w < wid) prefix += s;
            total += s;
        }
        if (i < N_NODES) row_ptr[i + 1] = carry + prefix + incl;
        carry += total;
        __syncthreads();
    }
    if (tid == 0) row_ptr[0] = 0;
}

// ---------------- CSR fill (by dst) with premultiplied symmetric norm ----------------
__global__ void fill_csr(const int* __restrict__ src, const int* __restrict__ dst,
                         const int* __restrict__ row_ptr, int* __restrict__ cursor,
                         const int* __restrict__ deg_out, const int* __restrict__ deg_in,
                         int* __restrict__ col, float* __restrict__ wv) {
    int e = blockIdx.x * blockDim.x + threadIdx.x;
    if (e >= N_EDGES) return;
    int s = src[e], d = dst[e];
    int pos = row_ptr[d] + atomicAdd(&cursor[d], 1);
    int ds = deg_out[s]; if (ds < 1) ds = 1;
    int dd = deg_in[d];  if (dd < 1) dd = 1;
    col[pos] = s;
    wv[pos] = (1.0f / sqrtf((float)ds)) * (1.0f / sqrtf((float)dd));
}

// ---------------- weight prep: transpose + bf16 ----------------
// fc1_wT[n][k]   n<128, k<256   from fc1_w[k][n] (256x128)
// WcatT[l][n][k] n<128, k<256   k<128: W1[l][k][n], k>=128: W2[l][k-128][n]
// fc2_wT[n][k]   n<64,  k<128   from fc2_w[k][n] (128x64)
__global__ void prep_w(const float* __restrict__ fc1_w,
                       const float* __restrict__ W1, const float* __restrict__ W2,
                       const float* __restrict__ fc2_w,
                       short* __restrict__ fc1_wT, short* __restrict__ WcatT,
                       short* __restrict__ fc2_wT) {
    int i = blockIdx.x * 256 + threadIdx.x;
    if (i < 128 * 256) {
        int n = i >> 8, k = i & 255;
        fc1_wT[i] = to_bf16(fc1_w[k * H_F + n]);
    }
    if (i < 4 * 128 * 256) {
        int l = i >> 15; int r = i & 32767; int n = r >> 8; int k = r & 255;
        float w = (k < 128) ? W1[l * 16384 + k * H_F + n]
                            : W2[l * 16384 + (k - 128) * H_F + n];
        WcatT[i] = to_bf16(w);
    }
    if (i < 64 * 128) {
        int n = i >> 7, k = i & 127;
        fc2_wT[i] = to_bf16(fc2_w[k * C_F + n]);
    }
}

#define CVT8(dstv, p, scale) {                                                  \
    float4 _v0 = *(const float4*)(p); float4 _v1 = *(const float4*)((p) + 4);   \
    dstv[0] = to_bf16((scale) * _v0.x); dstv[1] = to_bf16((scale) * _v0.y);     \
    dstv[2] = to_bf16((scale) * _v0.z); dstv[3] = to_bf16((scale) * _v0.w);     \
    dstv[4] = to_bf16((scale) * _v1.x); dstv[5] = to_bf16((scale) * _v1.y);     \
    dstv[6] = to_bf16((scale) * _v1.z); dstv[7] = to_bf16((scale) * _v1.w); }

// ---------------- fc1: h0 = relu(x @ fc1_w + b) via bf16 MFMA ----------------
// grid 625 blocks x 256 thr; wave handles 16 rows x 128 cols, K=256
__global__ __launch_bounds__(256) void fc1_mfma(const float* __restrict__ x,
                                                const short* __restrict__ wT,
                                                const float* __restrict__ b,
                                                float* __restrict__ h0) {
    int tid = threadIdx.x;
    int wave = tid >> 6, lane = tid & 63;
    int m = lane & 15, quad = lane >> 4;
    int row = blockIdx.x * 64 + wave * 16 + m;
    const float* xr = x + (size_t)row * IN_F + quad * 8;
    short8 afrag[8];
    #pragma unroll
    for (int ks = 0; ks < 8; ks++) {
        CVT8(afrag[ks], xr + ks * 32, 1.0f);
    }
    #pragma unroll
    for (int c = 0; c < 8; c += 2) {
        f32x4 acc0 = {0.f, 0.f, 0.f, 0.f};
        f32x4 acc1 = {0.f, 0.f, 0.f, 0.f};
        const short* b0p = wT + (size_t)(c * 16 + m) * IN_F + quad * 8;
        const short* b1p = b0p + 16 * IN_F;
        #pragma unroll
        for (int ks = 0; ks < 8; ks++) {
            short8 b0 = *(const short8*)(b0p + ks * 32);
            short8 b1 = *(const short8*)(b1p + ks * 32);
            acc0 = __builtin_amdgcn_mfma_f32_16x16x32_bf16(afrag[ks], b0, acc0, 0, 0, 0);
            acc1 = __builtin_amdgcn_mfma_f32_16x16x32_bf16(afrag[ks], b1, acc1, 0, 0, 0);
        }
        int col0 = c * 16 + m;
        int rbase = blockIdx.x * 64 + wave * 16 + quad * 4;
        float bg0 = b[col0], bg1 = b[col0 + 16];
        #pragma unroll
        for (int r = 0; r < 4; r++) {
            size_t idx = (size_t)(rbase + r) * H_F + col0;
            float v0 = acc0[r] + bg0;
            float v1 = acc1[r] + bg1;
            h0[idx] = v0 > 0.f ? v0 : 0.f;
            h0[idx + 16] = v1 > 0.f ? v1 : 0.f;
        }
    }
}

// ---------------- SpMM: agg[n] = sum_e wv[e] * h[col[e]] ----------------
__global__ __launch_bounds__(128) void spmm_kernel(const float* __restrict__ h,
                                                   const int* __restrict__ row_ptr,
                                                   const int* __restrict__ col,
                                                   const float* __restrict__ wv,
                                                   float* __restrict__ agg) {
    int n = blockIdx.x;
    int j = threadIdx.x;
    int e0 = row_ptr[n], e1 = row_ptr[n + 1];
    float acc = 0.f;
    for (int e = e0; e < e1; e++) {
        int c = col[e];
        float wgt = wv[e];
        acc += wgt * h[(size_t)c * H_F + j];
    }
    agg[(size_t)n * H_F + j] = acc;
}

// ---------------- combine via bf16 MFMA ----------------
// acc = [feat, f0] @ WcatT^T   (feat=0.5*agg, f0=0.5*h0, K=256)
// h_out = relu((1-beta)*0.5*(agg+h0) + beta*acc + bgc + h_in)
__global__ __launch_bounds__(256) void combine_mfma(const float* __restrict__ agg,
                                                    const float* __restrict__ h0,
                                                    const float* __restrict__ h_in,
                                                    const short* __restrict__ wT,
                                                    const float* __restrict__ bgc,
                                                    float beta,
                                                    float* __restrict__ h_out) {
    int tid = threadIdx.x;
    int wave = tid >> 6, lane = tid & 63;
    int m = lane & 15, quad = lane >> 4;
    int row = blockIdx.x * 64 + wave * 16 + m;
    const float* aggr = agg + (size_t)row * H_F + quad * 8;
    const float* h0r  = h0  + (size_t)row * H_F + quad * 8;
    short8 afrag[8];
    #pragma unroll
    for (int ks = 0; ks < 4; ks++) {
        CVT8(afrag[ks], aggr + ks * 32, 0.5f);
    }
    #pragma unroll
    for (int ks = 0; ks < 4; ks++) {
        CVT8(afrag[ks + 4], h0r + ks * 32, 0.5f);
    }
    float omb = 1.f - beta;
    #pragma unroll
    for (int c = 0; c < 8; c += 2) {
        f32x4 acc0 = {0.f, 0.f, 0.f, 0.f};
        f32x4 acc1 = {0.f, 0.f, 0.f, 0.f};
        const short* b0p = wT + (size_t)(c * 16 + m) * 256 + quad * 8;
        const short* b1p = b0p + 16 * 256;
        #pragma unroll
        for (int ks = 0; ks < 8; ks++) {
            short8 b0 = *(const short8*)(b0p + ks * 32);
            short8 b1 = *(const short8*)(b1p + ks * 32);
            acc0 = __builtin_amdgcn_mfma_f32_16x16x32_bf16(afrag[ks], b0, acc0, 0, 0, 0);
            acc1 = __builtin_amdgcn_mfma_f32_16x16x32_bf16(afrag[ks], b1, acc1, 0, 0, 0);
        }
        int col0 = c * 16 + m;
        int rbase = blockIdx.x * 64 + wave * 16 + quad * 4;
        float bg0 = bgc[col0], bg1 = bgc[col0 + 16];
        #pragma unroll
        for (int r = 0; r < 4; r++) {
            size_t idx = (size_t)(rbase + r) * H_F + col0;
            float s0 = 0.5f * (agg[idx] + h0[idx]);
            float s1 = 0.5f * (agg[idx + 16] + h0[idx + 16]);
            float v0 = omb * s0 + beta * acc0[r] + bg0 + h_in[idx];
            float v1 = omb * s1 + beta * acc1[r] + bg1 + h_in[idx + 16];
            h_out[idx] = v0 > 0.f ? v0 : 0.f;
            h_out[idx + 16] = v1 > 0.f ? v1 : 0.f;
        }
    }
}

// ---------------- fc2: out = h @ fc2_w + b via bf16 MFMA (K=128, 64 cols) ----
__global__ __launch_bounds__(256) void fc2_mfma(const float* __restrict__ h,
                                                const short* __restrict__ wT,
                                                const float* __restrict__ b,
                                                float* __restrict__ out) {
    int tid = threadIdx.x;
    int wave = tid >> 6, lane = tid & 63;
    int m = lane & 15, quad = lane >> 4;
    int row = blockIdx.x * 64 + wave * 16 + m;
    const float* hr = h + (size_t)row * H_F + quad * 8;
    short8 afrag[4];
    #pragma unroll
    for (int ks = 0; ks < 4; ks++) {
        CVT8(afrag[ks], hr + ks * 32, 1.0f);
    }
    #pragma unroll
    for (int c = 0; c < 4; c += 2) {
        f32x4 acc0 = {0.f, 0.f, 0.f, 0.f};
        f32x4 acc1 = {0.f, 0.f, 0.f, 0.f};
        const short* b0p = wT + (size_t)(c * 16 + m) * H_F + quad * 8;
        const short* b1p = b0p + 16 * H_F;
        #pragma unroll
        for (int ks = 0; ks < 4; ks++) {
            short8 b0 = *(const short8*)(b0p + ks * 32);
            short8 b1 = *(const short8*)(b1p + ks * 32);
            acc0 = __builtin_amdgcn_mfma_f32_16x16x32_bf16(afrag[ks], b0, acc0, 0, 0, 0);
            acc1 = __builtin_amdgcn_mfma_f32_16x16x32_bf16(afrag[ks], b1, acc1, 0, 0, 0);
        }
        int col0 = c * 16 + m;
        int rbase = blockIdx.x * 64 + wave * 16 + quad * 4;
        float bg0 = b[col0], bg1 = b[col0 + 16];
        #pragma unroll
        for (int r = 0; r < 4; r++) {
            size_t idx = (size_t)(rbase + r) * C_F + col0;
            out[idx] = acc0[r] + bg0;
            out[idx + 16] = acc1[r] + bg1;
        }
    }
}

extern "C" void kernel_launch(void* const* d_in, const int* in_sizes, int n_in,
                              void* d_out, int out_size, void* d_ws, size_t ws_size,
                              hipStream_t stream) {
    const float* x     = (const float*)d_in[0];
    const float* fc1_w = (const float*)d_in[1];
    const float* fc1_b = (const float*)d_in[2];
    const float* W1    = (const float*)d_in[3];
    const float* W2    = (const float*)d_in[4];
    const float* bgc   = (const float*)d_in[5];
    const float* fc2_w = (const float*)d_in[6];
    const float* fc2_b = (const float*)d_in[7];
    const int*   src   = (const int*)d_in[8];
    const int*   dst   = (const int*)d_in[9];
    float* out = (float*)d_out;

    char* p = (char*)d_ws;
    auto alloc = [&](size_t bytes) {
        char* r = p;
        p += (bytes + 255) & ~(size_t)255;
        return r;
    };
    int*   deg_out = (int*)alloc((size_t)N_NODES * 4);
    int*   deg_in  = (int*)alloc((size_t)N_NODES * 4);
    int*   row_ptr = (int*)alloc((size_t)(N_NODES + 1) * 4);
    int*   cursor  = (int*)alloc((size_t)N_NODES * 4);
    int*   col     = (int*)alloc((size_t)N_EDGES * 4);
    float* wv      = (float*)alloc((size_t)N_EDGES * 4);
    float* h0      = (float*)alloc((size_t)N_NODES * H_F * 4);
    float* hA      = (float*)alloc((size_t)N_NODES * H_F * 4);
    float* hB      = (float*)alloc((size_t)N_NODES * H_F * 4);
    float* agg     = (float*)alloc((size_t)N_NODES * H_F * 4);
    short* fc1_wT  = (short*)alloc((size_t)128 * 256 * 2);
    short* WcatT   = (short*)alloc((size_t)4 * 128 * 256 * 2);
    short* fc2_wT  = (short*)alloc((size_t)64 * 128 * 2);

    hipMemsetAsync(deg_out, 0, (size_t)N_NODES * 4, stream);
    hipMemsetAsync(deg_in,  0, (size_t)N_NODES * 4, stream);
    hipMemsetAsync(cursor,  0, (size_t)N_NODES * 4, stream);

    deg_kernel<<<(N_EDGES + 255) / 256, 256, 0, stream>>>(src, dst, deg_out, deg_in);
    scan_kernel<<<1, 1024, 0, stream>>>(deg_in, row_ptr);
    fill_csr<<<(N_EDGES + 255) / 256, 256, 0, stream>>>(src, dst, row_ptr, cursor,
                                                        deg_out, deg_in, col, wv);
    prep_w<<<512, 256, 0, stream>>>(fc1_w, W1, W2, fc2_w, fc1_wT, WcatT, fc2_wT);
    fc1_mfma<<<N_NODES / 64, 256, 0, stream>>>(x, fc1_wT, fc1_b, h0);

    const float* h_in = h0;
    float* bufs[2] = {hA, hB};
    for (int l = 0; l < L_LAYERS; l++) {
        float beta = (float)log(1.0 / (double)(l + 1) + 1.0);
        float* h_out = bufs[l & 1];
        spmm_kernel<<<N_NODES, 128, 0, stream>>>(h_in, row_ptr, col, wv, agg);
        combine_mfma<<<N_NODES / 64, 256, 0, stream>>>(agg, h0, h_in,
                                                       WcatT + (size_t)l * 128 * 256,
                                                       bgc + (size_t)l * H_F,
                                                       beta, h_out);
        h_in = h_out;
    }
    fc2_mfma<<<N_NODES / 64, 256, 0, stream>>>(h_in, fc2_wT, fc2_b, out);
}

// Round 3
// 567.212 us; speedup vs baseline: 1.5986x; 1.1936x over previous
//
#include <hip/hip_runtime.h>
#include <math.h>

#define N_NODES 40000
#define N_EDGES 640000
#define IN_F 256
#define H_F 128
#define C_F 64
#define L_LAYERS 4

typedef short short8 __attribute__((ext_vector_type(8)));
typedef float f32x4 __attribute__((ext_vector_type(4)));

__device__ inline short to_bf16(float f) {
    unsigned u = __builtin_bit_cast(unsigned, f);
    unsigned r = (u + 0x7FFFu + ((u >> 16) & 1u)) >> 16;
    return (short)r;
}

// ---------------- degree count ----------------
__global__ void deg_kernel(const int* __restrict__ src, const int* __restrict__ dst,
                           int* __restrict__ deg_out, int* __restrict__ deg_in) {
    int e = blockIdx.x * blockDim.x + threadIdx.x;
    if (e >= N_EDGES) return;
    atomicAdd(&deg_out[src[e]], 1);
    atomicAdd(&deg_in[dst[e]], 1);
}

// ---------------- exclusive prefix sum over deg_in -> row_ptr ----------------
__global__ void scan_kernel(const int* __restrict__ deg, int* __restrict__ row_ptr) {
    __shared__ int wsum[16];
    int tid = threadIdx.x;
    int lane = tid & 63, wid = tid >> 6;
    int carry = 0;
    for (int base = 0; base < N_NODES; base += 1024) {
        int i = base + tid;
        int v = (i < N_NODES) ? deg[i] : 0;
        int incl = v;
        #pragma unroll
        for (int off = 1; off < 64; off <<= 1) {
            int t = __shfl_up(incl, off, 64);
            if (lane >= off) incl += t;
        }
        if (lane == 63) wsum[wid] = incl;
        __syncthreads();
        int prefix = 0, total = 0;
        #pragma unroll
        for (int w = 0; w < 16; w++) {
            int s = wsum[w];
            if (w < wid) prefix += s;
            total += s;
        }
        if (i < N_NODES) row_ptr[i + 1] = carry + prefix + incl;
        carry += total;
        __syncthreads();
    }
    if (tid == 0) row_ptr[0] = 0;
}

// ---------------- CSR fill (by dst) with premultiplied symmetric norm ----------------
__global__ void fill_csr(const int* __restrict__ src, const int* __restrict__ dst,
                         const int* __restrict__ row_ptr, int* __restrict__ cursor,
                         const int* __restrict__ deg_out, const int* __restrict__ deg_in,
                         int* __restrict__ col, float* __restrict__ wv) {
    int e = blockIdx.x * blockDim.x + threadIdx.x;
    if (e >= N_EDGES) return;
    int s = src[e], d = dst[e];
    int pos = row_ptr[d] + atomicAdd(&cursor[d], 1);
    int ds = deg_out[s]; if (ds < 1) ds = 1;
    int dd = deg_in[d];  if (dd < 1) dd = 1;
    col[pos] = s;
    wv[pos] = (1.0f / sqrtf((float)ds)) * (1.0f / sqrtf((float)dd));
}

// ---------------- weight prep: transpose + bf16 ----------------
__global__ void prep_w(const float* __restrict__ fc1_w,
                       const float* __restrict__ W1, const float* __restrict__ W2,
                       const float* __restrict__ fc2_w,
                       short* __restrict__ fc1_wT, short* __restrict__ WcatT,
                       short* __restrict__ fc2_wT) {
    int i = blockIdx.x * 256 + threadIdx.x;
    if (i < 128 * 256) {
        int n = i >> 8, k = i & 255;
        fc1_wT[i] = to_bf16(fc1_w[k * H_F + n]);
    }
    if (i < 4 * 128 * 256) {
        int l = i >> 15; int r = i & 32767; int n = r >> 8; int k = r & 255;
        float w = (k < 128) ? W1[l * 16384 + k * H_F + n]
                            : W2[l * 16384 + (k - 128) * H_F + n];
        WcatT[i] = to_bf16(w);
    }
    if (i < 64 * 128) {
        int n = i >> 7, k = i & 127;
        fc2_wT[i] = to_bf16(fc2_w[k * C_F + n]);
    }
}

#define CVT8(dstv, p, scale) {                                                  \
    float4 _v0 = *(const float4*)(p); float4 _v1 = *(const float4*)((p) + 4);   \
    dstv[0] = to_bf16((scale) * _v0.x); dstv[1] = to_bf16((scale) * _v0.y);     \
    dstv[2] = to_bf16((scale) * _v0.z); dstv[3] = to_bf16((scale) * _v0.w);     \
    dstv[4] = to_bf16((scale) * _v1.x); dstv[5] = to_bf16((scale) * _v1.y);     \
    dstv[6] = to_bf16((scale) * _v1.z); dstv[7] = to_bf16((scale) * _v1.w); }

// ---------------- fc1: h0 = relu(x @ fc1_w + b) via bf16 MFMA ----------------
__global__ __launch_bounds__(256) void fc1_mfma(const float* __restrict__ x,
                                                const short* __restrict__ wT,
                                                const float* __restrict__ b,
                                                float* __restrict__ h0) {
    int tid = threadIdx.x;
    int wave = tid >> 6, lane = tid & 63;
    int m = lane & 15, quad = lane >> 4;
    int row = blockIdx.x * 64 + wave * 16 + m;
    const float* xr = x + (size_t)row * IN_F + quad * 8;
    short8 afrag[8];
    #pragma unroll
    for (int ks = 0; ks < 8; ks++) {
        CVT8(afrag[ks], xr + ks * 32, 1.0f);
    }
    #pragma unroll
    for (int c = 0; c < 8; c += 2) {
        f32x4 acc0 = {0.f, 0.f, 0.f, 0.f};
        f32x4 acc1 = {0.f, 0.f, 0.f, 0.f};
        const short* b0p = wT + (size_t)(c * 16 + m) * IN_F + quad * 8;
        const short* b1p = b0p + 16 * IN_F;
        #pragma unroll
        for (int ks = 0; ks < 8; ks++) {
            short8 b0 = *(const short8*)(b0p + ks * 32);
            short8 b1 = *(const short8*)(b1p + ks * 32);
            acc0 = __builtin_amdgcn_mfma_f32_16x16x32_bf16(afrag[ks], b0, acc0, 0, 0, 0);
            acc1 = __builtin_amdgcn_mfma_f32_16x16x32_bf16(afrag[ks], b1, acc1, 0, 0, 0);
        }
        int col0 = c * 16 + m;
        int rbase = blockIdx.x * 64 + wave * 16 + quad * 4;
        float bg0 = b[col0], bg1 = b[col0 + 16];
        #pragma unroll
        for (int r = 0; r < 4; r++) {
            size_t idx = (size_t)(rbase + r) * H_F + col0;
            float v0 = acc0[r] + bg0;
            float v1 = acc1[r] + bg1;
            h0[idx] = v0 > 0.f ? v0 : 0.f;
            h0[idx + 16] = v1 > 0.f ? v1 : 0.f;
        }
    }
}

// ---------------- SpMM v2: one wave per node, 4 edge slots x 16 lanes ----------
// lane = slot*16 + fi; each lane covers features [fi*4, fi*4+4) and [64+fi*4, ...)
// 8 independent gather streams per wave; cross-slot reduce via shfl_xor.
__global__ __launch_bounds__(256) void spmm_kernel(const float* __restrict__ h,
                                                   const int* __restrict__ row_ptr,
                                                   const int* __restrict__ col,
                                                   const float* __restrict__ wv,
                                                   float* __restrict__ agg) {
    int wave = threadIdx.x >> 6, lane = threadIdx.x & 63;
    int slot = lane >> 4, fi = lane & 15;
    int n = blockIdx.x * 4 + wave;
    int e0 = row_ptr[n], e1 = row_ptr[n + 1];
    float a0x = 0.f, a0y = 0.f, a0z = 0.f, a0w = 0.f;
    float a1x = 0.f, a1y = 0.f, a1z = 0.f, a1w = 0.f;
    for (int e = e0 + slot; e < e1; e += 4) {
        int c = col[e];
        float w = wv[e];
        const float4* hp = (const float4*)(h + (size_t)c * H_F) + fi;
        float4 v0 = hp[0];
        float4 v1 = hp[16];
        a0x += w * v0.x; a0y += w * v0.y; a0z += w * v0.z; a0w += w * v0.w;
        a1x += w * v1.x; a1y += w * v1.y; a1z += w * v1.z; a1w += w * v1.w;
    }
    #pragma unroll
    for (int mask = 16; mask <= 32; mask <<= 1) {
        a0x += __shfl_xor(a0x, mask, 64); a0y += __shfl_xor(a0y, mask, 64);
        a0z += __shfl_xor(a0z, mask, 64); a0w += __shfl_xor(a0w, mask, 64);
        a1x += __shfl_xor(a1x, mask, 64); a1y += __shfl_xor(a1y, mask, 64);
        a1z += __shfl_xor(a1z, mask, 64); a1w += __shfl_xor(a1w, mask, 64);
    }
    if (slot == 0) {
        float4* ap = (float4*)(agg + (size_t)n * H_F) + fi;
        float4 r0 = {a0x, a0y, a0z, a0w};
        float4 r1 = {a1x, a1y, a1z, a1w};
        ap[0] = r0;
        ap[16] = r1;
    }
}

// ---------------- combine via bf16 MFMA ----------------
__global__ __launch_bounds__(256) void combine_mfma(const float* __restrict__ agg,
                                                    const float* __restrict__ h0,
                                                    const float* __restrict__ h_in,
                                                    const short* __restrict__ wT,
                                                    const float* __restrict__ bgc,
                                                    float beta,
                                                    float* __restrict__ h_out) {
    int tid = threadIdx.x;
    int wave = tid >> 6, lane = tid & 63;
    int m = lane & 15, quad = lane >> 4;
    int row = blockIdx.x * 64 + wave * 16 + m;
    const float* aggr = agg + (size_t)row * H_F + quad * 8;
    const float* h0r  = h0  + (size_t)row * H_F + quad * 8;
    short8 afrag[8];
    #pragma unroll
    for (int ks = 0; ks < 4; ks++) {
        CVT8(afrag[ks], aggr + ks * 32, 0.5f);
    }
    #pragma unroll
    for (int ks = 0; ks < 4; ks++) {
        CVT8(afrag[ks + 4], h0r + ks * 32, 0.5f);
    }
    float omb = 1.f - beta;
    #pragma unroll
    for (int c = 0; c < 8; c += 2) {
        f32x4 acc0 = {0.f, 0.f, 0.f, 0.f};
        f32x4 acc1 = {0.f, 0.f, 0.f, 0.f};
        const short* b0p = wT + (size_t)(c * 16 + m) * 256 + quad * 8;
        const short* b1p = b0p + 16 * 256;
        #pragma unroll
        for (int ks = 0; ks < 8; ks++) {
            short8 b0 = *(const short8*)(b0p + ks * 32);
            short8 b1 = *(const short8*)(b1p + ks * 32);
            acc0 = __builtin_amdgcn_mfma_f32_16x16x32_bf16(afrag[ks], b0, acc0, 0, 0, 0);
            acc1 = __builtin_amdgcn_mfma_f32_16x16x32_bf16(afrag[ks], b1, acc1, 0, 0, 0);
        }
        int col0 = c * 16 + m;
        int rbase = blockIdx.x * 64 + wave * 16 + quad * 4;
        float bg0 = bgc[col0], bg1 = bgc[col0 + 16];
        #pragma unroll
        for (int r = 0; r < 4; r++) {
            size_t idx = (size_t)(rbase + r) * H_F + col0;
            float s0 = 0.5f * (agg[idx] + h0[idx]);
            float s1 = 0.5f * (agg[idx + 16] + h0[idx + 16]);
            float v0 = omb * s0 + beta * acc0[r] + bg0 + h_in[idx];
            float v1 = omb * s1 + beta * acc1[r] + bg1 + h_in[idx + 16];
            h_out[idx] = v0 > 0.f ? v0 : 0.f;
            h_out[idx + 16] = v1 > 0.f ? v1 : 0.f;
        }
    }
}

// ---------------- fc2: out = h @ fc2_w + b via bf16 MFMA (K=128, 64 cols) ----
__global__ __launch_bounds__(256) void fc2_mfma(const float* __restrict__ h,
                                                const short* __restrict__ wT,
                                                const float* __restrict__ b,
                                                float* __restrict__ out) {
    int tid = threadIdx.x;
    int wave = tid >> 6, lane = tid & 63;
    int m = lane & 15, quad = lane >> 4;
    int row = blockIdx.x * 64 + wave * 16 + m;
    const float* hr = h + (size_t)row * H_F + quad * 8;
    short8 afrag[4];
    #pragma unroll
    for (int ks = 0; ks < 4; ks++) {
        CVT8(afrag[ks], hr + ks * 32, 1.0f);
    }
    #pragma unroll
    for (int c = 0; c < 4; c += 2) {
        f32x4 acc0 = {0.f, 0.f, 0.f, 0.f};
        f32x4 acc1 = {0.f, 0.f, 0.f, 0.f};
        const short* b0p = wT + (size_t)(c * 16 + m) * H_F + quad * 8;
        const short* b1p = b0p + 16 * H_F;
        #pragma unroll
        for (int ks = 0; ks < 4; ks++) {
            short8 b0 = *(const short8*)(b0p + ks * 32);
            short8 b1 = *(const short8*)(b1p + ks * 32);
            acc0 = __builtin_amdgcn_mfma_f32_16x16x32_bf16(afrag[ks], b0, acc0, 0, 0, 0);
            acc1 = __builtin_amdgcn_mfma_f32_16x16x32_bf16(afrag[ks], b1, acc1, 0, 0, 0);
        }
        int col0 = c * 16 + m;
        int rbase = blockIdx.x * 64 + wave * 16 + quad * 4;
        float bg0 = b[col0], bg1 = b[col0 + 16];
        #pragma unroll
        for (int r = 0; r < 4; r++) {
            size_t idx = (size_t)(rbase + r) * C_F + col0;
            out[idx] = acc0[r] + bg0;
            out[idx + 16] = acc1[r] + bg1;
        }
    }
}

extern "C" void kernel_launch(void* const* d_in, const int* in_sizes, int n_in,
                              void* d_out, int out_size, void* d_ws, size_t ws_size,
                              hipStream_t stream) {
    const float* x     = (const float*)d_in[0];
    const float* fc1_w = (const float*)d_in[1];
    const float* fc1_b = (const float*)d_in[2];
    const float* W1    = (const float*)d_in[3];
    const float* W2    = (const float*)d_in[4];
    const float* bgc   = (const float*)d_in[5];
    const float* fc2_w = (const float*)d_in[6];
    const float* fc2_b = (const float*)d_in[7];
    const int*   src   = (const int*)d_in[8];
    const int*   dst   = (const int*)d_in[9];
    float* out = (float*)d_out;

    char* p = (char*)d_ws;
    auto alloc = [&](size_t bytes) {
        char* r = p;
        p += (bytes + 255) & ~(size_t)255;
        return r;
    };
    int*   deg_out = (int*)alloc((size_t)N_NODES * 4);
    int*   deg_in  = (int*)alloc((size_t)N_NODES * 4);
    int*   row_ptr = (int*)alloc((size_t)(N_NODES + 1) * 4);
    int*   cursor  = (int*)alloc((size_t)N_NODES * 4);
    int*   col     = (int*)alloc((size_t)N_EDGES * 4);
    float* wv      = (float*)alloc((size_t)N_EDGES * 4);
    float* h0      = (float*)alloc((size_t)N_NODES * H_F * 4);
    float* hA      = (float*)alloc((size_t)N_NODES * H_F * 4);
    float* hB      = (float*)alloc((size_t)N_NODES * H_F * 4);
    float* agg     = (float*)alloc((size_t)N_NODES * H_F * 4);
    short* fc1_wT  = (short*)alloc((size_t)128 * 256 * 2);
    short* WcatT   = (short*)alloc((size_t)4 * 128 * 256 * 2);
    short* fc2_wT  = (short*)alloc((size_t)64 * 128 * 2);

    hipMemsetAsync(deg_out, 0, (size_t)N_NODES * 4, stream);
    hipMemsetAsync(deg_in,  0, (size_t)N_NODES * 4, stream);
    hipMemsetAsync(cursor,  0, (size_t)N_NODES * 4, stream);

    deg_kernel<<<(N_EDGES + 255) / 256, 256, 0, stream>>>(src, dst, deg_out, deg_in);
    scan_kernel<<<1, 1024, 0, stream>>>(deg_in, row_ptr);
    fill_csr<<<(N_EDGES + 255) / 256, 256, 0, stream>>>(src, dst, row_ptr, cursor,
                                                        deg_out, deg_in, col, wv);
    prep_w<<<512, 256, 0, stream>>>(fc1_w, W1, W2, fc2_w, fc1_wT, WcatT, fc2_wT);
    fc1_mfma<<<N_NODES / 64, 256, 0, stream>>>(x, fc1_wT, fc1_b, h0);

    const float* h_in = h0;
    float* bufs[2] = {hA, hB};
    for (int l = 0; l < L_LAYERS; l++) {
        float beta = (float)log(1.0 / (double)(l + 1) + 1.0);
        float* h_out = bufs[l & 1];
        spmm_kernel<<<N_NODES / 4, 256, 0, stream>>>(h_in, row_ptr, col, wv, agg);
        combine_mfma<<<N_NODES / 64, 256, 0, stream>>>(agg, h0, h_in,
                                                       WcatT + (size_t)l * 128 * 256,
                                                       bgc + (size_t)l * H_F,
                                                       beta, h_out);
        h_in = h_out;
    }
    fc2_mfma<<<N_NODES / 64, 256, 0, stream>>>(h_in, fc2_wT, fc2_b, out);
}

// Round 4
// 520.825 us; speedup vs baseline: 1.7410x; 1.0891x over previous
//
#include <hip/hip_runtime.h>
#include <math.h>

#define N_NODES 40000
#define N_EDGES 640000
#define IN_F 256
#define H_F 128
#define C_F 64
#define L_LAYERS 4
#define SCAN_BLKS 157   // ceil(40000/256)

typedef short short8 __attribute__((ext_vector_type(8)));
typedef float f32x4 __attribute__((ext_vector_type(4)));

__device__ inline short to_bf16(float f) {
    unsigned u = __builtin_bit_cast(unsigned, f);
    unsigned r = (u + 0x7FFFu + ((u >> 16) & 1u)) >> 16;
    return (short)r;
}

// 256-thread block exclusive scan; returns excl; *tot = block total
__device__ inline int block_excl_scan(int v, int* wsum, int* tot) {
    int tid = threadIdx.x;
    int lane = tid & 63, wid = tid >> 6;
    int incl = v;
    #pragma unroll
    for (int off = 1; off < 64; off <<= 1) {
        int t = __shfl_up(incl, off, 64);
        if (lane >= off) incl += t;
    }
    if (lane == 63) wsum[wid] = incl;
    __syncthreads();
    int prefix = 0, total = 0;
    #pragma unroll
    for (int w = 0; w < 4; w++) {
        int s = wsum[w];
        if (w < wid) prefix += s;
        total += s;
    }
    *tot = total;
    return prefix + incl - v;
}

// ---------------- weight prep: transpose + bf16 ----------------
__global__ void prep_w(const float* __restrict__ fc1_w,
                       const float* __restrict__ W1, const float* __restrict__ W2,
                       const float* __restrict__ fc2_w,
                       short* __restrict__ fc1_wT, short* __restrict__ WcatT,
                       short* __restrict__ fc2_wT) {
    int i = blockIdx.x * 256 + threadIdx.x;
    if (i < 128 * 256) {
        int n = i >> 8, k = i & 255;
        fc1_wT[i] = to_bf16(fc1_w[k * H_F + n]);
    }
    if (i < 4 * 128 * 256) {
        int l = i >> 15; int r = i & 32767; int n = r >> 8; int k = r & 255;
        float w = (k < 128) ? W1[l * 16384 + k * H_F + n]
                            : W2[l * 16384 + (k - 128) * H_F + n];
        WcatT[i] = to_bf16(w);
    }
    if (i < 64 * 128) {
        int n = i >> 7, k = i & 127;
        fc2_wT[i] = to_bf16(fc2_w[k * C_F + n]);
    }
}

#define CVT8(dstv, p, scale) {                                                  \
    float4 _v0 = *(const float4*)(p); float4 _v1 = *(const float4*)((p) + 4);   \
    dstv[0] = to_bf16((scale) * _v0.x); dstv[1] = to_bf16((scale) * _v0.y);     \
    dstv[2] = to_bf16((scale) * _v0.z); dstv[3] = to_bf16((scale) * _v0.w);     \
    dstv[4] = to_bf16((scale) * _v1.x); dstv[5] = to_bf16((scale) * _v1.y);     \
    dstv[6] = to_bf16((scale) * _v1.z); dstv[7] = to_bf16((scale) * _v1.w); }

// ---------------- K1: heterogeneous grid — deg+pos (atomic fabric) || fc1 (MFMA)
// blocks [0,2500): edge pass; blocks [2500,3125): fc1 rows
__global__ __launch_bounds__(256) void deg_fc1_fused(const int* __restrict__ src,
                                                     const int* __restrict__ dst,
                                                     int* __restrict__ cnt_out,
                                                     int* __restrict__ cnt_in,
                                                     unsigned short* __restrict__ pos16,
                                                     const float* __restrict__ x,
                                                     const short* __restrict__ wT,
                                                     const float* __restrict__ b,
                                                     float* __restrict__ h0) {
    int blk = blockIdx.x;
    if (blk < 2500) {
        int e = blk * 256 + threadIdx.x;
        int s = src[e], d = dst[e];
        pos16[e] = (unsigned short)atomicAdd(&cnt_in[d], 1);
        atomicAdd(&cnt_out[s], 1);
        return;
    }
    int bb = blk - 2500;
    int tid = threadIdx.x;
    int wave = tid >> 6, lane = tid & 63;
    int m = lane & 15, quad = lane >> 4;
    int row = bb * 64 + wave * 16 + m;
    const float* xr = x + (size_t)row * IN_F + quad * 8;
    short8 afrag[8];
    #pragma unroll
    for (int ks = 0; ks < 8; ks++) {
        CVT8(afrag[ks], xr + ks * 32, 1.0f);
    }
    #pragma unroll
    for (int c = 0; c < 8; c += 2) {
        f32x4 acc0 = {0.f, 0.f, 0.f, 0.f};
        f32x4 acc1 = {0.f, 0.f, 0.f, 0.f};
        const short* b0p = wT + (size_t)(c * 16 + m) * IN_F + quad * 8;
        const short* b1p = b0p + 16 * IN_F;
        #pragma unroll
        for (int ks = 0; ks < 8; ks++) {
            short8 b0 = *(const short8*)(b0p + ks * 32);
            short8 b1 = *(const short8*)(b1p + ks * 32);
            acc0 = __builtin_amdgcn_mfma_f32_16x16x32_bf16(afrag[ks], b0, acc0, 0, 0, 0);
            acc1 = __builtin_amdgcn_mfma_f32_16x16x32_bf16(afrag[ks], b1, acc1, 0, 0, 0);
        }
        int col0 = c * 16 + m;
        int rbase = bb * 64 + wave * 16 + quad * 4;
        float bg0 = b[col0], bg1 = b[col0 + 16];
        #pragma unroll
        for (int r = 0; r < 4; r++) {
            size_t idx = (size_t)(rbase + r) * H_F + col0;
            float v0 = acc0[r] + bg0;
            float v1 = acc1[r] + bg1;
            h0[idx] = v0 > 0.f ? v0 : 0.f;
            h0[idx + 16] = v1 > 0.f ? v1 : 0.f;
        }
    }
}

// ---------------- K2a: per-256-chunk exclusive scan of cnt_in ----------------
__global__ __launch_bounds__(256) void scan1(const int* __restrict__ cnt_in,
                                             int* __restrict__ row_local,
                                             int* __restrict__ blk_sum) {
    __shared__ int wsum[4];
    int n = blockIdx.x * 256 + threadIdx.x;
    int v = (n < N_NODES) ? cnt_in[n] : 0;
    int tot;
    int excl = block_excl_scan(v, wsum, &tot);
    if (n < N_NODES) row_local[n] = excl;
    if (threadIdx.x == 0) blk_sum[blockIdx.x] = tot;
}

// ---------------- K2b: scan of block sums ----------------
__global__ __launch_bounds__(256) void scan2(const int* __restrict__ blk_sum,
                                             int* __restrict__ blk_off) {
    __shared__ int wsum[4];
    int t = threadIdx.x;
    int v = (t < SCAN_BLKS) ? blk_sum[t] : 0;
    int tot;
    int excl = block_excl_scan(v, wsum, &tot);
    if (t < SCAN_BLKS) blk_off[t] = excl;
}

// ---------------- K3: atomic-free CSR fill + row_ptr materialize ----------------
// blocks [0,2500): edges; blocks [2500, 2500+157): row_ptr
__global__ __launch_bounds__(256) void fill_fused(const int* __restrict__ src,
                                                  const int* __restrict__ dst,
                                                  const unsigned short* __restrict__ pos16,
                                                  const int* __restrict__ cnt_out,
                                                  const int* __restrict__ cnt_in,
                                                  const int* __restrict__ row_local,
                                                  const int* __restrict__ blk_off,
                                                  int* __restrict__ col,
                                                  float* __restrict__ wv,
                                                  int* __restrict__ row_ptr) {
    int blk = blockIdx.x;
    if (blk < 2500) {
        int e = blk * 256 + threadIdx.x;
        int s = src[e], d = dst[e];
        int rp = blk_off[d >> 8] + row_local[d] + (int)pos16[e];
        int ds = cnt_out[s]; if (ds < 1) ds = 1;
        int dd = cnt_in[d];  if (dd < 1) dd = 1;
        col[rp] = s;
        wv[rp] = (1.0f / sqrtf((float)ds)) * (1.0f / sqrtf((float)dd));
        return;
    }
    int n = (blk - 2500) * 256 + threadIdx.x;
    if (n < N_NODES) row_ptr[n] = blk_off[n >> 8] + row_local[n];
    if (blk == 2500 && threadIdx.x == 0) row_ptr[N_NODES] = N_EDGES;
}

// ---------------- SpMM: one wave per node, 4 slots x 16 lanes, unroll x2 -------
__global__ __launch_bounds__(256) void spmm_kernel(const float* __restrict__ h,
                                                   const int* __restrict__ row_ptr,
                                                   const int* __restrict__ col,
                                                   const float* __restrict__ wv,
                                                   float* __restrict__ agg) {
    int wave = threadIdx.x >> 6, lane = threadIdx.x & 63;
    int slot = lane >> 4, fi = lane & 15;
    int n = blockIdx.x * 4 + wave;
    int e0 = row_ptr[n], e1 = row_ptr[n + 1];
    float a0x = 0.f, a0y = 0.f, a0z = 0.f, a0w = 0.f;
    float a1x = 0.f, a1y = 0.f, a1z = 0.f, a1w = 0.f;
    int e = e0 + slot;
    for (; e + 4 < e1; e += 8) {
        int c0 = col[e];       float w0 = wv[e];
        int c1 = col[e + 4];   float w1 = wv[e + 4];
        const float4* hp0 = (const float4*)(h + (size_t)c0 * H_F) + fi;
        const float4* hp1 = (const float4*)(h + (size_t)c1 * H_F) + fi;
        float4 v00 = hp0[0];
        float4 v01 = hp0[16];
        float4 v10 = hp1[0];
        float4 v11 = hp1[16];
        a0x += w0 * v00.x; a0y += w0 * v00.y; a0z += w0 * v00.z; a0w += w0 * v00.w;
        a1x += w0 * v01.x; a1y += w0 * v01.y; a1z += w0 * v01.z; a1w += w0 * v01.w;
        a0x += w1 * v10.x; a0y += w1 * v10.y; a0z += w1 * v10.z; a0w += w1 * v10.w;
        a1x += w1 * v11.x; a1y += w1 * v11.y; a1z += w1 * v11.z; a1w += w1 * v11.w;
    }
    if (e < e1) {
        int c = col[e];
        float w = wv[e];
        const float4* hp = (const float4*)(h + (size_t)c * H_F) + fi;
        float4 v0 = hp[0];
        float4 v1 = hp[16];
        a0x += w * v0.x; a0y += w * v0.y; a0z += w * v0.z; a0w += w * v0.w;
        a1x += w * v1.x; a1y += w * v1.y; a1z += w * v1.z; a1w += w * v1.w;
    }
    #pragma unroll
    for (int mask = 16; mask <= 32; mask <<= 1) {
        a0x += __shfl_xor(a0x, mask, 64); a0y += __shfl_xor(a0y, mask, 64);
        a0z += __shfl_xor(a0z, mask, 64); a0w += __shfl_xor(a0w, mask, 64);
        a1x += __shfl_xor(a1x, mask, 64); a1y += __shfl_xor(a1y, mask, 64);
        a1z += __shfl_xor(a1z, mask, 64); a1w += __shfl_xor(a1w, mask, 64);
    }
    if (slot == 0) {
        float4* ap = (float4*)(agg + (size_t)n * H_F) + fi;
        float4 r0 = {a0x, a0y, a0z, a0w};
        float4 r1 = {a1x, a1y, a1z, a1w};
        ap[0] = r0;
        ap[16] = r1;
    }
}

// ---------------- combine via bf16 MFMA ----------------
__global__ __launch_bounds__(256) void combine_mfma(const float* __restrict__ agg,
                                                    const float* __restrict__ h0,
                                                    const float* __restrict__ h_in,
                                                    const short* __restrict__ wT,
                                                    const float* __restrict__ bgc,
                                                    float beta,
                                                    float* __restrict__ h_out) {
    int tid = threadIdx.x;
    int wave = tid >> 6, lane = tid & 63;
    int m = lane & 15, quad = lane >> 4;
    int row = blockIdx.x * 64 + wave * 16 + m;
    const float* aggr = agg + (size_t)row * H_F + quad * 8;
    const float* h0r  = h0  + (size_t)row * H_F + quad * 8;
    short8 afrag[8];
    #pragma unroll
    for (int ks = 0; ks < 4; ks++) {
        CVT8(afrag[ks], aggr + ks * 32, 0.5f);
    }
    #pragma unroll
    for (int ks = 0; ks < 4; ks++) {
        CVT8(afrag[ks + 4], h0r + ks * 32, 0.5f);
    }
    float omb = 1.f - beta;
    #pragma unroll
    for (int c = 0; c < 8; c += 2) {
        f32x4 acc0 = {0.f, 0.f, 0.f, 0.f};
        f32x4 acc1 = {0.f, 0.f, 0.f, 0.f};
        const short* b0p = wT + (size_t)(c * 16 + m) * 256 + quad * 8;
        const short* b1p = b0p + 16 * 256;
        #pragma unroll
        for (int ks = 0; ks < 8; ks++) {
            short8 b0 = *(const short8*)(b0p + ks * 32);
            short8 b1 = *(const short8*)(b1p + ks * 32);
            acc0 = __builtin_amdgcn_mfma_f32_16x16x32_bf16(afrag[ks], b0, acc0, 0, 0, 0);
            acc1 = __builtin_amdgcn_mfma_f32_16x16x32_bf16(afrag[ks], b1, acc1, 0, 0, 0);
        }
        int col0 = c * 16 + m;
        int rbase = blockIdx.x * 64 + wave * 16 + quad * 4;
        float bg0 = bgc[col0], bg1 = bgc[col0 + 16];
        #pragma unroll
        for (int r = 0; r < 4; r++) {
            size_t idx = (size_t)(rbase + r) * H_F + col0;
            float s0 = 0.5f * (agg[idx] + h0[idx]);
            float s1 = 0.5f * (agg[idx + 16] + h0[idx + 16]);
            float v0 = omb * s0 + beta * acc0[r] + bg0 + h_in[idx];
            float v1 = omb * s1 + beta * acc1[r] + bg1 + h_in[idx + 16];
            h_out[idx] = v0 > 0.f ? v0 : 0.f;
            h_out[idx + 16] = v1 > 0.f ? v1 : 0.f;
        }
    }
}

// ---------------- fc2: out = h @ fc2_w + b via bf16 MFMA ----------------
__global__ __launch_bounds__(256) void fc2_mfma(const float* __restrict__ h,
                                                const short* __restrict__ wT,
                                                const float* __restrict__ b,
                                                float* __restrict__ out) {
    int tid = threadIdx.x;
    int wave = tid >> 6, lane = tid & 63;
    int m = lane & 15, quad = lane >> 4;
    int row = blockIdx.x * 64 + wave * 16 + m;
    const float* hr = h + (size_t)row * H_F + quad * 8;
    short8 afrag[4];
    #pragma unroll
    for (int ks = 0; ks < 4; ks++) {
        CVT8(afrag[ks], hr + ks * 32, 1.0f);
    }
    #pragma unroll
    for (int c = 0; c < 4; c += 2) {
        f32x4 acc0 = {0.f, 0.f, 0.f, 0.f};
        f32x4 acc1 = {0.f, 0.f, 0.f, 0.f};
        const short* b0p = wT + (size_t)(c * 16 + m) * H_F + quad * 8;
        const short* b1p = b0p + 16 * H_F;
        #pragma unroll
        for (int ks = 0; ks < 4; ks++) {
            short8 b0 = *(const short8*)(b0p + ks * 32);
            short8 b1 = *(const short8*)(b1p + ks * 32);
            acc0 = __builtin_amdgcn_mfma_f32_16x16x32_bf16(afrag[ks], b0, acc0, 0, 0, 0);
            acc1 = __builtin_amdgcn_mfma_f32_16x16x32_bf16(afrag[ks], b1, acc1, 0, 0, 0);
        }
        int col0 = c * 16 + m;
        int rbase = blockIdx.x * 64 + wave * 16 + quad * 4;
        float bg0 = b[col0], bg1 = b[col0 + 16];
        #pragma unroll
        for (int r = 0; r < 4; r++) {
            size_t idx = (size_t)(rbase + r) * C_F + col0;
            out[idx] = acc0[r] + bg0;
            out[idx + 16] = acc1[r] + bg1;
        }
    }
}

extern "C" void kernel_launch(void* const* d_in, const int* in_sizes, int n_in,
                              void* d_out, int out_size, void* d_ws, size_t ws_size,
                              hipStream_t stream) {
    const float* x     = (const float*)d_in[0];
    const float* fc1_w = (const float*)d_in[1];
    const float* fc1_b = (const float*)d_in[2];
    const float* W1    = (const float*)d_in[3];
    const float* W2    = (const float*)d_in[4];
    const float* bgc   = (const float*)d_in[5];
    const float* fc2_w = (const float*)d_in[6];
    const float* fc2_b = (const float*)d_in[7];
    const int*   src   = (const int*)d_in[8];
    const int*   dst   = (const int*)d_in[9];
    float* out = (float*)d_out;

    char* p = (char*)d_ws;
    auto alloc = [&](size_t bytes) {
        char* r = p;
        p += (bytes + 255) & ~(size_t)255;
        return r;
    };
    int*   cnt_out   = (int*)alloc((size_t)N_NODES * 4);
    int*   cnt_in    = (int*)alloc((size_t)N_NODES * 4);
    int*   row_ptr   = (int*)alloc((size_t)(N_NODES + 1) * 4);
    int*   row_local = (int*)alloc((size_t)N_NODES * 4);
    int*   blk_sum   = (int*)alloc((size_t)SCAN_BLKS * 4);
    int*   blk_off   = (int*)alloc((size_t)SCAN_BLKS * 4);
    unsigned short* pos16 = (unsigned short*)alloc((size_t)N_EDGES * 2);
    int*   col     = (int*)alloc((size_t)N_EDGES * 4);
    float* wv      = (float*)alloc((size_t)N_EDGES * 4);
    float* h0      = (float*)alloc((size_t)N_NODES * H_F * 4);
    float* hA      = (float*)alloc((size_t)N_NODES * H_F * 4);
    float* hB      = (float*)alloc((size_t)N_NODES * H_F * 4);
    float* agg     = (float*)alloc((size_t)N_NODES * H_F * 4);
    short* fc1_wT  = (short*)alloc((size_t)128 * 256 * 2);
    short* WcatT   = (short*)alloc((size_t)4 * 128 * 256 * 2);
    short* fc2_wT  = (short*)alloc((size_t)64 * 128 * 2);

    hipMemsetAsync(cnt_out, 0, (size_t)N_NODES * 4, stream);
    hipMemsetAsync(cnt_in,  0, (size_t)N_NODES * 4, stream);

    prep_w<<<512, 256, 0, stream>>>(fc1_w, W1, W2, fc2_w, fc1_wT, WcatT, fc2_wT);
    deg_fc1_fused<<<3125, 256, 0, stream>>>(src, dst, cnt_out, cnt_in, pos16,
                                            x, fc1_wT, fc1_b, h0);
    scan1<<<SCAN_BLKS, 256, 0, stream>>>(cnt_in, row_local, blk_sum);
    scan2<<<1, 256, 0, stream>>>(blk_sum, blk_off);
    fill_fused<<<2500 + SCAN_BLKS, 256, 0, stream>>>(src, dst, pos16, cnt_out, cnt_in,
                                                     row_local, blk_off, col, wv, row_ptr);

    const float* h_in = h0;
    float* bufs[2] = {hA, hB};
    for (int l = 0; l < L_LAYERS; l++) {
        float beta = (float)log(1.0 / (double)(l + 1) + 1.0);
        float* h_out = bufs[l & 1];
        spmm_kernel<<<N_NODES / 4, 256, 0, stream>>>(h_in, row_ptr, col, wv, agg);
        combine_mfma<<<N_NODES / 64, 256, 0, stream>>>(agg, h0, h_in,
                                                       WcatT + (size_t)l * 128 * 256,
                                                       bgc + (size_t)l * H_F,
                                                       beta, h_out);
        h_in = h_out;
    }
    fc2_mfma<<<N_NODES / 64, 256, 0, stream>>>(h_in, fc2_wT, fc2_b, out);
}

// Round 5
// 447.154 us; speedup vs baseline: 2.0278x; 1.1648x over previous
//
#include <hip/hip_runtime.h>
#include <math.h>

#define N_NODES 40000
#define N_EDGES 640000
#define IN_F 256
#define H_F 128
#define C_F 64
#define L_LAYERS 4
#define SCAN_BLKS 157   // ceil(40000/256)

typedef short short8 __attribute__((ext_vector_type(8)));
typedef unsigned short ushort8 __attribute__((ext_vector_type(8)));
typedef float f32x4 __attribute__((ext_vector_type(4)));

__device__ inline short to_bf16(float f) {
    unsigned u = __builtin_bit_cast(unsigned, f);
    unsigned r = (u + 0x7FFFu + ((u >> 16) & 1u)) >> 16;
    return (short)r;
}
__device__ inline float bf16_to_f(unsigned short u) {
    unsigned v = ((unsigned)u) << 16;
    return __builtin_bit_cast(float, v);
}

// 256-thread block exclusive scan; returns excl; *tot = block total
__device__ inline int block_excl_scan(int v, int* wsum, int* tot) {
    int tid = threadIdx.x;
    int lane = tid & 63, wid = tid >> 6;
    int incl = v;
    #pragma unroll
    for (int off = 1; off < 64; off <<= 1) {
        int t = __shfl_up(incl, off, 64);
        if (lane >= off) incl += t;
    }
    if (lane == 63) wsum[wid] = incl;
    __syncthreads();
    int prefix = 0, total = 0;
    #pragma unroll
    for (int w = 0; w < 4; w++) {
        int s = wsum[w];
        if (w < wid) prefix += s;
        total += s;
    }
    *tot = total;
    return prefix + incl - v;
}

// ---------------- weight prep: transpose + bf16 ----------------
__global__ void prep_w(const float* __restrict__ fc1_w,
                       const float* __restrict__ W1, const float* __restrict__ W2,
                       const float* __restrict__ fc2_w,
                       short* __restrict__ fc1_wT, short* __restrict__ WcatT,
                       short* __restrict__ fc2_wT) {
    int i = blockIdx.x * 256 + threadIdx.x;
    if (i < 128 * 256) {
        int n = i >> 8, k = i & 255;
        fc1_wT[i] = to_bf16(fc1_w[k * H_F + n]);
    }
    if (i < 4 * 128 * 256) {
        int l = i >> 15; int r = i & 32767; int n = r >> 8; int k = r & 255;
        float w = (k < 128) ? W1[l * 16384 + k * H_F + n]
                            : W2[l * 16384 + (k - 128) * H_F + n];
        WcatT[i] = to_bf16(w);
    }
    if (i < 64 * 128) {
        int n = i >> 7, k = i & 127;
        fc2_wT[i] = to_bf16(fc2_w[k * C_F + n]);
    }
}

#define CVT8(dstv, p, scale) {                                                  \
    float4 _v0 = *(const float4*)(p); float4 _v1 = *(const float4*)((p) + 4);   \
    dstv[0] = to_bf16((scale) * _v0.x); dstv[1] = to_bf16((scale) * _v0.y);     \
    dstv[2] = to_bf16((scale) * _v0.z); dstv[3] = to_bf16((scale) * _v0.w);     \
    dstv[4] = to_bf16((scale) * _v1.x); dstv[5] = to_bf16((scale) * _v1.y);     \
    dstv[6] = to_bf16((scale) * _v1.z); dstv[7] = to_bf16((scale) * _v1.w); }

// ---------------- K1: heterogeneous grid — deg+pos (atomic fabric) || fc1 (MFMA)
// blocks [0,2500): edge pass; blocks [2500,3125): fc1 rows
// fc1 writes fp32 h0 AND bf16 h0b (spmm layer-0 input).
__global__ __launch_bounds__(256) void deg_fc1_fused(const int* __restrict__ src,
                                                     const int* __restrict__ dst,
                                                     int* __restrict__ cnt_out,
                                                     int* __restrict__ cnt_in,
                                                     unsigned short* __restrict__ pos16,
                                                     const float* __restrict__ x,
                                                     const short* __restrict__ wT,
                                                     const float* __restrict__ b,
                                                     float* __restrict__ h0,
                                                     unsigned short* __restrict__ h0b) {
    int blk = blockIdx.x;
    if (blk < 2500) {
        int e = blk * 256 + threadIdx.x;
        int s = src[e], d = dst[e];
        pos16[e] = (unsigned short)atomicAdd(&cnt_in[d], 1);
        atomicAdd(&cnt_out[s], 1);
        return;
    }
    int bb = blk - 2500;
    int tid = threadIdx.x;
    int wave = tid >> 6, lane = tid & 63;
    int m = lane & 15, quad = lane >> 4;
    int row = bb * 64 + wave * 16 + m;
    const float* xr = x + (size_t)row * IN_F + quad * 8;
    short8 afrag[8];
    #pragma unroll
    for (int ks = 0; ks < 8; ks++) {
        CVT8(afrag[ks], xr + ks * 32, 1.0f);
    }
    #pragma unroll
    for (int c = 0; c < 8; c += 2) {
        f32x4 acc0 = {0.f, 0.f, 0.f, 0.f};
        f32x4 acc1 = {0.f, 0.f, 0.f, 0.f};
        const short* b0p = wT + (size_t)(c * 16 + m) * IN_F + quad * 8;
        const short* b1p = b0p + 16 * IN_F;
        #pragma unroll
        for (int ks = 0; ks < 8; ks++) {
            short8 b0 = *(const short8*)(b0p + ks * 32);
            short8 b1 = *(const short8*)(b1p + ks * 32);
            acc0 = __builtin_amdgcn_mfma_f32_16x16x32_bf16(afrag[ks], b0, acc0, 0, 0, 0);
            acc1 = __builtin_amdgcn_mfma_f32_16x16x32_bf16(afrag[ks], b1, acc1, 0, 0, 0);
        }
        int col0 = c * 16 + m;
        int rbase = bb * 64 + wave * 16 + quad * 4;
        float bg0 = b[col0], bg1 = b[col0 + 16];
        #pragma unroll
        for (int r = 0; r < 4; r++) {
            size_t idx = (size_t)(rbase + r) * H_F + col0;
            float v0 = acc0[r] + bg0;
            float v1 = acc1[r] + bg1;
            v0 = v0 > 0.f ? v0 : 0.f;
            v1 = v1 > 0.f ? v1 : 0.f;
            h0[idx] = v0;
            h0[idx + 16] = v1;
            h0b[idx] = (unsigned short)to_bf16(v0);
            h0b[idx + 16] = (unsigned short)to_bf16(v1);
        }
    }
}

// ---------------- K2a/K2b: hierarchical scan ----------------
__global__ __launch_bounds__(256) void scan1(const int* __restrict__ cnt_in,
                                             int* __restrict__ row_local,
                                             int* __restrict__ blk_sum) {
    __shared__ int wsum[4];
    int n = blockIdx.x * 256 + threadIdx.x;
    int v = (n < N_NODES) ? cnt_in[n] : 0;
    int tot;
    int excl = block_excl_scan(v, wsum, &tot);
    if (n < N_NODES) row_local[n] = excl;
    if (threadIdx.x == 0) blk_sum[blockIdx.x] = tot;
}

__global__ __launch_bounds__(256) void scan2(const int* __restrict__ blk_sum,
                                             int* __restrict__ blk_off) {
    __shared__ int wsum[4];
    int t = threadIdx.x;
    int v = (t < SCAN_BLKS) ? blk_sum[t] : 0;
    int tot;
    int excl = block_excl_scan(v, wsum, &tot);
    if (t < SCAN_BLKS) blk_off[t] = excl;
}

// ---------------- K3: atomic-free CSR fill + row_ptr materialize ----------------
__global__ __launch_bounds__(256) void fill_fused(const int* __restrict__ src,
                                                  const int* __restrict__ dst,
                                                  const unsigned short* __restrict__ pos16,
                                                  const int* __restrict__ cnt_out,
                                                  const int* __restrict__ cnt_in,
                                                  const int* __restrict__ row_local,
                                                  const int* __restrict__ blk_off,
                                                  int* __restrict__ col,
                                                  float* __restrict__ wv,
                                                  int* __restrict__ row_ptr) {
    int blk = blockIdx.x;
    if (blk < 2500) {
        int e = blk * 256 + threadIdx.x;
        int s = src[e], d = dst[e];
        int rp = blk_off[d >> 8] + row_local[d] + (int)pos16[e];
        int ds = cnt_out[s]; if (ds < 1) ds = 1;
        int dd = cnt_in[d];  if (dd < 1) dd = 1;
        col[rp] = s;
        wv[rp] = (1.0f / sqrtf((float)ds)) * (1.0f / sqrtf((float)dd));
        return;
    }
    int n = (blk - 2500) * 256 + threadIdx.x;
    if (n < N_NODES) row_ptr[n] = blk_off[n >> 8] + row_local[n];
    if (blk == 2500 && threadIdx.x == 0) row_ptr[N_NODES] = N_EDGES;
}

// ---------------- SpMM (bf16 h): one wave per node, 4 slots x 16 lanes --------
// Row = 128 bf16 = 256B; lane fi covers features [fi*8, fi*8+8) = one 16B load.
// Unroll x4 over edge slots: up to 4 gathers in flight per lane.
__global__ __launch_bounds__(256) void spmm_kernel(const unsigned short* __restrict__ hb,
                                                   const int* __restrict__ row_ptr,
                                                   const int* __restrict__ col,
                                                   const float* __restrict__ wv,
                                                   float* __restrict__ agg) {
    int wave = threadIdx.x >> 6, lane = threadIdx.x & 63;
    int slot = lane >> 4, fi = lane & 15;
    int n = blockIdx.x * 4 + wave;
    int e0 = row_ptr[n], e1 = row_ptr[n + 1];
    float a[8] = {};
    int e = e0 + slot;
    for (; e + 12 < e1; e += 16) {
        int c0 = col[e];      float w0 = wv[e];
        int c1 = col[e + 4];  float w1 = wv[e + 4];
        int c2 = col[e + 8];  float w2 = wv[e + 8];
        int c3 = col[e + 12]; float w3 = wv[e + 12];
        ushort8 u0 = *(const ushort8*)(hb + (size_t)c0 * H_F + fi * 8);
        ushort8 u1 = *(const ushort8*)(hb + (size_t)c1 * H_F + fi * 8);
        ushort8 u2 = *(const ushort8*)(hb + (size_t)c2 * H_F + fi * 8);
        ushort8 u3 = *(const ushort8*)(hb + (size_t)c3 * H_F + fi * 8);
        #pragma unroll
        for (int j = 0; j < 8; j++) {
            a[j] += w0 * bf16_to_f(u0[j]) + w1 * bf16_to_f(u1[j])
                  + w2 * bf16_to_f(u2[j]) + w3 * bf16_to_f(u3[j]);
        }
    }
    for (; e < e1; e += 4) {
        int c = col[e];
        float w = wv[e];
        ushort8 u = *(const ushort8*)(hb + (size_t)c * H_F + fi * 8);
        #pragma unroll
        for (int j = 0; j < 8; j++) a[j] += w * bf16_to_f(u[j]);
    }
    #pragma unroll
    for (int mask = 16; mask <= 32; mask <<= 1) {
        #pragma unroll
        for (int j = 0; j < 8; j++) a[j] += __shfl_xor(a[j], mask, 64);
    }
    if (slot == 0) {
        float4* ap = (float4*)(agg + (size_t)n * H_F + fi * 8);
        float4 r0 = {a[0], a[1], a[2], a[3]};
        float4 r1 = {a[4], a[5], a[6], a[7]};
        ap[0] = r0;
        ap[1] = r1;
    }
}

// ---------------- combine via bf16 MFMA; writes fp32 h_out + bf16 copy -------
__global__ __launch_bounds__(256) void combine_mfma(const float* __restrict__ agg,
                                                    const float* __restrict__ h0,
                                                    const float* __restrict__ h_in,
                                                    const short* __restrict__ wT,
                                                    const float* __restrict__ bgc,
                                                    float beta,
                                                    float* __restrict__ h_out,
                                                    unsigned short* __restrict__ h_outb) {
    int tid = threadIdx.x;
    int wave = tid >> 6, lane = tid & 63;
    int m = lane & 15, quad = lane >> 4;
    int row = blockIdx.x * 64 + wave * 16 + m;
    const float* aggr = agg + (size_t)row * H_F + quad * 8;
    const float* h0r  = h0  + (size_t)row * H_F + quad * 8;
    short8 afrag[8];
    #pragma unroll
    for (int ks = 0; ks < 4; ks++) {
        CVT8(afrag[ks], aggr + ks * 32, 0.5f);
    }
    #pragma unroll
    for (int ks = 0; ks < 4; ks++) {
        CVT8(afrag[ks + 4], h0r + ks * 32, 0.5f);
    }
    float omb = 1.f - beta;
    #pragma unroll
    for (int c = 0; c < 8; c += 2) {
        f32x4 acc0 = {0.f, 0.f, 0.f, 0.f};
        f32x4 acc1 = {0.f, 0.f, 0.f, 0.f};
        const short* b0p = wT + (size_t)(c * 16 + m) * 256 + quad * 8;
        const short* b1p = b0p + 16 * 256;
        #pragma unroll
        for (int ks = 0; ks < 8; ks++) {
            short8 b0 = *(const short8*)(b0p + ks * 32);
            short8 b1 = *(const short8*)(b1p + ks * 32);
            acc0 = __builtin_amdgcn_mfma_f32_16x16x32_bf16(afrag[ks], b0, acc0, 0, 0, 0);
            acc1 = __builtin_amdgcn_mfma_f32_16x16x32_bf16(afrag[ks], b1, acc1, 0, 0, 0);
        }
        int col0 = c * 16 + m;
        int rbase = blockIdx.x * 64 + wave * 16 + quad * 4;
        float bg0 = bgc[col0], bg1 = bgc[col0 + 16];
        #pragma unroll
        for (int r = 0; r < 4; r++) {
            size_t idx = (size_t)(rbase + r) * H_F + col0;
            float s0 = 0.5f * (agg[idx] + h0[idx]);
            float s1 = 0.5f * (agg[idx + 16] + h0[idx + 16]);
            float v0 = omb * s0 + beta * acc0[r] + bg0 + h_in[idx];
            float v1 = omb * s1 + beta * acc1[r] + bg1 + h_in[idx + 16];
            v0 = v0 > 0.f ? v0 : 0.f;
            v1 = v1 > 0.f ? v1 : 0.f;
            h_out[idx] = v0;
            h_out[idx + 16] = v1;
            h_outb[idx] = (unsigned short)to_bf16(v0);
            h_outb[idx + 16] = (unsigned short)to_bf16(v1);
        }
    }
}

// ---------------- fc2: out = h @ fc2_w + b via bf16 MFMA ----------------
__global__ __launch_bounds__(256) void fc2_mfma(const float* __restrict__ h,
                                                const short* __restrict__ wT,
                                                const float* __restrict__ b,
                                                float* __restrict__ out) {
    int tid = threadIdx.x;
    int wave = tid >> 6, lane = tid & 63;
    int m = lane & 15, quad = lane >> 4;
    int row = blockIdx.x * 64 + wave * 16 + m;
    const float* hr = h + (size_t)row * H_F + quad * 8;
    short8 afrag[4];
    #pragma unroll
    for (int ks = 0; ks < 4; ks++) {
        CVT8(afrag[ks], hr + ks * 32, 1.0f);
    }
    #pragma unroll
    for (int c = 0; c < 4; c += 2) {
        f32x4 acc0 = {0.f, 0.f, 0.f, 0.f};
        f32x4 acc1 = {0.f, 0.f, 0.f, 0.f};
        const short* b0p = wT + (size_t)(c * 16 + m) * H_F + quad * 8;
        const short* b1p = b0p + 16 * H_F;
        #pragma unroll
        for (int ks = 0; ks < 4; ks++) {
            short8 b0 = *(const short8*)(b0p + ks * 32);
            short8 b1 = *(const short8*)(b1p + ks * 32);
            acc0 = __builtin_amdgcn_mfma_f32_16x16x32_bf16(afrag[ks], b0, acc0, 0, 0, 0);
            acc1 = __builtin_amdgcn_mfma_f32_16x16x32_bf16(afrag[ks], b1, acc1, 0, 0, 0);
        }
        int col0 = c * 16 + m;
        int rbase = blockIdx.x * 64 + wave * 16 + quad * 4;
        float bg0 = b[col0], bg1 = b[col0 + 16];
        #pragma unroll
        for (int r = 0; r < 4; r++) {
            size_t idx = (size_t)(rbase + r) * C_F + col0;
            out[idx] = acc0[r] + bg0;
            out[idx + 16] = acc1[r] + bg1;
        }
    }
}

extern "C" void kernel_launch(void* const* d_in, const int* in_sizes, int n_in,
                              void* d_out, int out_size, void* d_ws, size_t ws_size,
                              hipStream_t stream) {
    const float* x     = (const float*)d_in[0];
    const float* fc1_w = (const float*)d_in[1];
    const float* fc1_b = (const float*)d_in[2];
    const float* W1    = (const float*)d_in[3];
    const float* W2    = (const float*)d_in[4];
    const float* bgc   = (const float*)d_in[5];
    const float* fc2_w = (const float*)d_in[6];
    const float* fc2_b = (const float*)d_in[7];
    const int*   src   = (const int*)d_in[8];
    const int*   dst   = (const int*)d_in[9];
    float* out = (float*)d_out;

    char* p = (char*)d_ws;
    auto alloc = [&](size_t bytes) {
        char* r = p;
        p += (bytes + 255) & ~(size_t)255;
        return r;
    };
    int*   cnt_out   = (int*)alloc((size_t)N_NODES * 4);
    int*   cnt_in    = (int*)alloc((size_t)N_NODES * 4);
    int*   row_ptr   = (int*)alloc((size_t)(N_NODES + 1) * 4);
    int*   row_local = (int*)alloc((size_t)N_NODES * 4);
    int*   blk_sum   = (int*)alloc((size_t)SCAN_BLKS * 4);
    int*   blk_off   = (int*)alloc((size_t)SCAN_BLKS * 4);
    unsigned short* pos16 = (unsigned short*)alloc((size_t)N_EDGES * 2);
    int*   col     = (int*)alloc((size_t)N_EDGES * 4);
    float* wv      = (float*)alloc((size_t)N_EDGES * 4);
    float* h0      = (float*)alloc((size_t)N_NODES * H_F * 4);
    float* hA      = (float*)alloc((size_t)N_NODES * H_F * 4);
    float* hB      = (float*)alloc((size_t)N_NODES * H_F * 4);
    float* agg     = (float*)alloc((size_t)N_NODES * H_F * 4);
    unsigned short* h0b = (unsigned short*)alloc((size_t)N_NODES * H_F * 2);
    unsigned short* hAb = (unsigned short*)alloc((size_t)N_NODES * H_F * 2);
    unsigned short* hBb = (unsigned short*)alloc((size_t)N_NODES * H_F * 2);
    short* fc1_wT  = (short*)alloc((size_t)128 * 256 * 2);
    short* WcatT   = (short*)alloc((size_t)4 * 128 * 256 * 2);
    short* fc2_wT  = (short*)alloc((size_t)64 * 128 * 2);

    hipMemsetAsync(cnt_out, 0, (size_t)N_NODES * 4, stream);
    hipMemsetAsync(cnt_in,  0, (size_t)N_NODES * 4, stream);

    prep_w<<<512, 256, 0, stream>>>(fc1_w, W1, W2, fc2_w, fc1_wT, WcatT, fc2_wT);
    deg_fc1_fused<<<3125, 256, 0, stream>>>(src, dst, cnt_out, cnt_in, pos16,
                                            x, fc1_wT, fc1_b, h0, h0b);
    scan1<<<SCAN_BLKS, 256, 0, stream>>>(cnt_in, row_local, blk_sum);
    scan2<<<1, 256, 0, stream>>>(blk_sum, blk_off);
    fill_fused<<<2500 + SCAN_BLKS, 256, 0, stream>>>(src, dst, pos16, cnt_out, cnt_in,
                                                     row_local, blk_off, col, wv, row_ptr);

    const float* h_in = h0;
    const unsigned short* h_in_b = h0b;
    float* bufs[2] = {hA, hB};
    unsigned short* bufsb[2] = {hAb, hBb};
    for (int l = 0; l < L_LAYERS; l++) {
        float beta = (float)log(1.0 / (double)(l + 1) + 1.0);
        float* h_out = bufs[l & 1];
        unsigned short* h_outb = bufsb[l & 1];
        spmm_kernel<<<N_NODES / 4, 256, 0, stream>>>(h_in_b, row_ptr, col, wv, agg);
        combine_mfma<<<N_NODES / 64, 256, 0, stream>>>(agg, h0, h_in,
                                                       WcatT + (size_t)l * 128 * 256,
                                                       bgc + (size_t)l * H_F,
                                                       beta, h_out, h_outb);
        h_in = h_out;
        h_in_b = h_outb;
    }
    fc2_mfma<<<N_NODES / 64, 256, 0, stream>>>(h_in, fc2_wT, fc2_b, out);
}

// Round 6
// 428.679 us; speedup vs baseline: 2.1152x; 1.0431x over previous
//
#include <hip/hip_runtime.h>
#include <math.h>

#define N_NODES 40000
#define N_EDGES 640000
#define IN_F 256
#define H_F 128
#define C_F 64
#define L_LAYERS 4
#define SCAN_BLKS 157   // ceil(40000/256)

typedef short short8 __attribute__((ext_vector_type(8)));
typedef unsigned short ushort8 __attribute__((ext_vector_type(8)));
typedef float f32x4 __attribute__((ext_vector_type(4)));

__device__ inline short to_bf16(float f) {
    unsigned u = __builtin_bit_cast(unsigned, f);
    unsigned r = (u + 0x7FFFu + ((u >> 16) & 1u)) >> 16;
    return (short)r;
}
__device__ inline float bf16_to_f(unsigned short u) {
    unsigned v = ((unsigned)u) << 16;
    return __builtin_bit_cast(float, v);
}

// 256-thread block exclusive scan; returns excl; *tot = block total
__device__ inline int block_excl_scan(int v, int* wsum, int* tot) {
    int tid = threadIdx.x;
    int lane = tid & 63, wid = tid >> 6;
    int incl = v;
    #pragma unroll
    for (int off = 1; off < 64; off <<= 1) {
        int t = __shfl_up(incl, off, 64);
        if (lane >= off) incl += t;
    }
    if (lane == 63) wsum[wid] = incl;
    __syncthreads();
    int prefix = 0, total = 0;
    #pragma unroll
    for (int w = 0; w < 4; w++) {
        int s = wsum[w];
        if (w < wid) prefix += s;
        total += s;
    }
    *tot = total;
    return prefix + incl - v;
}

// ---------------- weight prep: transpose + bf16 ----------------
// WcatT is pre-scaled by 0.5 (ALPHA folded in): acc = 0.5*(agg@W1 + h0@W2)
__global__ void prep_w(const float* __restrict__ fc1_w,
                       const float* __restrict__ W1, const float* __restrict__ W2,
                       const float* __restrict__ fc2_w,
                       short* __restrict__ fc1_wT, short* __restrict__ WcatT,
                       short* __restrict__ fc2_wT) {
    int i = blockIdx.x * 256 + threadIdx.x;
    if (i < 128 * 256) {
        int n = i >> 8, k = i & 255;
        fc1_wT[i] = to_bf16(fc1_w[k * H_F + n]);
    }
    if (i < 4 * 128 * 256) {
        int l = i >> 15; int r = i & 32767; int n = r >> 8; int k = r & 255;
        float w = (k < 128) ? W1[l * 16384 + k * H_F + n]
                            : W2[l * 16384 + (k - 128) * H_F + n];
        WcatT[i] = to_bf16(0.5f * w);
    }
    if (i < 64 * 128) {
        int n = i >> 7, k = i & 127;
        fc2_wT[i] = to_bf16(fc2_w[k * C_F + n]);
    }
}

#define CVT8(dstv, p) {                                                         \
    float4 _v0 = *(const float4*)(p); float4 _v1 = *(const float4*)((p) + 4);   \
    dstv[0] = to_bf16(_v0.x); dstv[1] = to_bf16(_v0.y);                         \
    dstv[2] = to_bf16(_v0.z); dstv[3] = to_bf16(_v0.w);                         \
    dstv[4] = to_bf16(_v1.x); dstv[5] = to_bf16(_v1.y);                         \
    dstv[6] = to_bf16(_v1.z); dstv[7] = to_bf16(_v1.w); }

// ---------------- K1: parity-interleaved — deg+pos (atomic fabric) || fc1 (MFMA)
// even blocks: 1024 edges each (625 blocks); odd blocks: fc1 rows (625 blocks).
// Parity interleave keeps both kinds resident so fc1 hides under atomic drain.
__global__ __launch_bounds__(256) void deg_fc1_fused(const int* __restrict__ src,
                                                     const int* __restrict__ dst,
                                                     int* __restrict__ cnt_out,
                                                     int* __restrict__ cnt_in,
                                                     unsigned short* __restrict__ pos16,
                                                     const float* __restrict__ x,
                                                     const short* __restrict__ wT,
                                                     const float* __restrict__ b,
                                                     unsigned short* __restrict__ h0b) {
    int blk = blockIdx.x;
    if ((blk & 1) == 0) {
        int e0 = (blk >> 1) * 1024 + threadIdx.x * 4;
        int4 s4 = *(const int4*)(src + e0);
        int4 d4 = *(const int4*)(dst + e0);
        pos16[e0 + 0] = (unsigned short)atomicAdd(&cnt_in[d4.x], 1);
        pos16[e0 + 1] = (unsigned short)atomicAdd(&cnt_in[d4.y], 1);
        pos16[e0 + 2] = (unsigned short)atomicAdd(&cnt_in[d4.z], 1);
        pos16[e0 + 3] = (unsigned short)atomicAdd(&cnt_in[d4.w], 1);
        atomicAdd(&cnt_out[s4.x], 1);
        atomicAdd(&cnt_out[s4.y], 1);
        atomicAdd(&cnt_out[s4.z], 1);
        atomicAdd(&cnt_out[s4.w], 1);
        return;
    }
    int bb = blk >> 1;
    int tid = threadIdx.x;
    int wave = tid >> 6, lane = tid & 63;
    int m = lane & 15, quad = lane >> 4;
    int row = bb * 64 + wave * 16 + m;
    const float* xr = x + (size_t)row * IN_F + quad * 8;
    short8 afrag[8];
    #pragma unroll
    for (int ks = 0; ks < 8; ks++) {
        CVT8(afrag[ks], xr + ks * 32);
    }
    #pragma unroll
    for (int c = 0; c < 8; c += 2) {
        f32x4 acc0 = {0.f, 0.f, 0.f, 0.f};
        f32x4 acc1 = {0.f, 0.f, 0.f, 0.f};
        const short* b0p = wT + (size_t)(c * 16 + m) * IN_F + quad * 8;
        const short* b1p = b0p + 16 * IN_F;
        #pragma unroll
        for (int ks = 0; ks < 8; ks++) {
            short8 b0 = *(const short8*)(b0p + ks * 32);
            short8 b1 = *(const short8*)(b1p + ks * 32);
            acc0 = __builtin_amdgcn_mfma_f32_16x16x32_bf16(afrag[ks], b0, acc0, 0, 0, 0);
            acc1 = __builtin_amdgcn_mfma_f32_16x16x32_bf16(afrag[ks], b1, acc1, 0, 0, 0);
        }
        int col0 = c * 16 + m;
        int rbase = bb * 64 + wave * 16 + quad * 4;
        float bg0 = b[col0], bg1 = b[col0 + 16];
        #pragma unroll
        for (int r = 0; r < 4; r++) {
            size_t idx = (size_t)(rbase + r) * H_F + col0;
            float v0 = acc0[r] + bg0;
            float v1 = acc1[r] + bg1;
            v0 = v0 > 0.f ? v0 : 0.f;
            v1 = v1 > 0.f ? v1 : 0.f;
            h0b[idx] = (unsigned short)to_bf16(v0);
            h0b[idx + 16] = (unsigned short)to_bf16(v1);
        }
    }
}

// ---------------- K2a/K2b: hierarchical scan ----------------
__global__ __launch_bounds__(256) void scan1(const int* __restrict__ cnt_in,
                                             int* __restrict__ row_local,
                                             int* __restrict__ blk_sum) {
    __shared__ int wsum[4];
    int n = blockIdx.x * 256 + threadIdx.x;
    int v = (n < N_NODES) ? cnt_in[n] : 0;
    int tot;
    int excl = block_excl_scan(v, wsum, &tot);
    if (n < N_NODES) row_local[n] = excl;
    if (threadIdx.x == 0) blk_sum[blockIdx.x] = tot;
}

__global__ __launch_bounds__(256) void scan2(const int* __restrict__ blk_sum,
                                             int* __restrict__ blk_off) {
    __shared__ int wsum[4];
    int t = threadIdx.x;
    int v = (t < SCAN_BLKS) ? blk_sum[t] : 0;
    int tot;
    int excl = block_excl_scan(v, wsum, &tot);
    if (t < SCAN_BLKS) blk_off[t] = excl;
}

// ---------------- K3: atomic-free CSR fill + row_ptr materialize ----------------
__global__ __launch_bounds__(256) void fill_fused(const int* __restrict__ src,
                                                  const int* __restrict__ dst,
                                                  const unsigned short* __restrict__ pos16,
                                                  const int* __restrict__ cnt_out,
                                                  const int* __restrict__ cnt_in,
                                                  const int* __restrict__ row_local,
                                                  const int* __restrict__ blk_off,
                                                  int* __restrict__ col,
                                                  float* __restrict__ wv,
                                                  int* __restrict__ row_ptr) {
    int blk = blockIdx.x;
    if (blk < 2500) {
        int e = blk * 256 + threadIdx.x;
        int s = src[e], d = dst[e];
        int rp = blk_off[d >> 8] + row_local[d] + (int)pos16[e];
        int ds = cnt_out[s]; if (ds < 1) ds = 1;
        int dd = cnt_in[d];  if (dd < 1) dd = 1;
        col[rp] = s;
        wv[rp] = (1.0f / sqrtf((float)ds)) * (1.0f / sqrtf((float)dd));
        return;
    }
    int n = (blk - 2500) * 256 + threadIdx.x;
    if (n < N_NODES) row_ptr[n] = blk_off[n >> 8] + row_local[n];
    if (blk == 2500 && threadIdx.x == 0) row_ptr[N_NODES] = N_EDGES;
}

// ---------------- SpMM (bf16 h): one wave per node, 4 slots x 16 lanes --------
__global__ __launch_bounds__(256) void spmm_kernel(const unsigned short* __restrict__ hb,
                                                   const int* __restrict__ row_ptr,
                                                   const int* __restrict__ col,
                                                   const float* __restrict__ wv,
                                                   float* __restrict__ agg) {
    int wave = threadIdx.x >> 6, lane = threadIdx.x & 63;
    int slot = lane >> 4, fi = lane & 15;
    int n = blockIdx.x * 4 + wave;
    int e0 = row_ptr[n], e1 = row_ptr[n + 1];
    float a[8] = {};
    int e = e0 + slot;
    for (; e + 12 < e1; e += 16) {
        int c0 = col[e];      float w0 = wv[e];
        int c1 = col[e + 4];  float w1 = wv[e + 4];
        int c2 = col[e + 8];  float w2 = wv[e + 8];
        int c3 = col[e + 12]; float w3 = wv[e + 12];
        ushort8 u0 = *(const ushort8*)(hb + (size_t)c0 * H_F + fi * 8);
        ushort8 u1 = *(const ushort8*)(hb + (size_t)c1 * H_F + fi * 8);
        ushort8 u2 = *(const ushort8*)(hb + (size_t)c2 * H_F + fi * 8);
        ushort8 u3 = *(const ushort8*)(hb + (size_t)c3 * H_F + fi * 8);
        #pragma unroll
        for (int j = 0; j < 8; j++) {
            a[j] += w0 * bf16_to_f(u0[j]) + w1 * bf16_to_f(u1[j])
                  + w2 * bf16_to_f(u2[j]) + w3 * bf16_to_f(u3[j]);
        }
    }
    for (; e < e1; e += 4) {
        int c = col[e];
        float w = wv[e];
        ushort8 u = *(const ushort8*)(hb + (size_t)c * H_F + fi * 8);
        #pragma unroll
        for (int j = 0; j < 8; j++) a[j] += w * bf16_to_f(u[j]);
    }
    #pragma unroll
    for (int mask = 16; mask <= 32; mask <<= 1) {
        #pragma unroll
        for (int j = 0; j < 8; j++) a[j] += __shfl_xor(a[j], mask, 64);
    }
    if (slot == 0) {
        float4* ap = (float4*)(agg + (size_t)n * H_F + fi * 8);
        float4 r0 = {a[0], a[1], a[2], a[3]};
        float4 r1 = {a[4], a[5], a[6], a[7]};
        ap[0] = r0;
        ap[1] = r1;
    }
}

// ---------------- combine via bf16 MFMA ----------------
// A = [agg(bf16-rounded), h0b]; W pre-scaled by 0.5 => acc = feat@W1 + f0@W2.
// identity from h_in_f (fp32) if non-null else h_in_b (bf16, layer 0).
// h_out fp32 skipped when null (last layer); h_outb always written.
__global__ __launch_bounds__(256) void combine_mfma(const float* __restrict__ agg,
                                                    const unsigned short* __restrict__ h0b,
                                                    const float* __restrict__ h_in_f,
                                                    const unsigned short* __restrict__ h_in_b,
                                                    const short* __restrict__ wT,
                                                    const float* __restrict__ bgc,
                                                    float beta,
                                                    float* __restrict__ h_out,
                                                    unsigned short* __restrict__ h_outb) {
    int tid = threadIdx.x;
    int wave = tid >> 6, lane = tid & 63;
    int m = lane & 15, quad = lane >> 4;
    int row = blockIdx.x * 64 + wave * 16 + m;
    const float* aggr = agg + (size_t)row * H_F + quad * 8;
    const unsigned short* h0r = h0b + (size_t)row * H_F + quad * 8;
    short8 afrag[8];
    #pragma unroll
    for (int ks = 0; ks < 4; ks++) {
        CVT8(afrag[ks], aggr + ks * 32);
    }
    #pragma unroll
    for (int ks = 0; ks < 4; ks++) {
        afrag[ks + 4] = __builtin_bit_cast(short8, *(const ushort8*)(h0r + ks * 32));
    }
    float omb = 1.f - beta;
    #pragma unroll
    for (int c = 0; c < 8; c += 2) {
        f32x4 acc0 = {0.f, 0.f, 0.f, 0.f};
        f32x4 acc1 = {0.f, 0.f, 0.f, 0.f};
        const short* b0p = wT + (size_t)(c * 16 + m) * 256 + quad * 8;
        const short* b1p = b0p + 16 * 256;
        #pragma unroll
        for (int ks = 0; ks < 8; ks++) {
            short8 b0 = *(const short8*)(b0p + ks * 32);
            short8 b1 = *(const short8*)(b1p + ks * 32);
            acc0 = __builtin_amdgcn_mfma_f32_16x16x32_bf16(afrag[ks], b0, acc0, 0, 0, 0);
            acc1 = __builtin_amdgcn_mfma_f32_16x16x32_bf16(afrag[ks], b1, acc1, 0, 0, 0);
        }
        int col0 = c * 16 + m;
        int rbase = blockIdx.x * 64 + wave * 16 + quad * 4;
        float bg0 = bgc[col0], bg1 = bgc[col0 + 16];
        #pragma unroll
        for (int r = 0; r < 4; r++) {
            size_t idx = (size_t)(rbase + r) * H_F + col0;
            float s0 = 0.5f * (agg[idx] + bf16_to_f(h0b[idx]));
            float s1 = 0.5f * (agg[idx + 16] + bf16_to_f(h0b[idx + 16]));
            float id0 = h_in_f ? h_in_f[idx] : bf16_to_f(h_in_b[idx]);
            float id1 = h_in_f ? h_in_f[idx + 16] : bf16_to_f(h_in_b[idx + 16]);
            float v0 = omb * s0 + beta * acc0[r] + bg0 + id0;
            float v1 = omb * s1 + beta * acc1[r] + bg1 + id1;
            v0 = v0 > 0.f ? v0 : 0.f;
            v1 = v1 > 0.f ? v1 : 0.f;
            if (h_out) {
                h_out[idx] = v0;
                h_out[idx + 16] = v1;
            }
            h_outb[idx] = (unsigned short)to_bf16(v0);
            h_outb[idx + 16] = (unsigned short)to_bf16(v1);
        }
    }
}

// ---------------- fc2: out = h(bf16) @ fc2_w + b via bf16 MFMA ----------------
__global__ __launch_bounds__(256) void fc2_mfma(const unsigned short* __restrict__ hb,
                                                const short* __restrict__ wT,
                                                const float* __restrict__ b,
                                                float* __restrict__ out) {
    int tid = threadIdx.x;
    int wave = tid >> 6, lane = tid & 63;
    int m = lane & 15, quad = lane >> 4;
    int row = blockIdx.x * 64 + wave * 16 + m;
    const unsigned short* hr = hb + (size_t)row * H_F + quad * 8;
    short8 afrag[4];
    #pragma unroll
    for (int ks = 0; ks < 4; ks++) {
        afrag[ks] = __builtin_bit_cast(short8, *(const ushort8*)(hr + ks * 32));
    }
    #pragma unroll
    for (int c = 0; c < 4; c += 2) {
        f32x4 acc0 = {0.f, 0.f, 0.f, 0.f};
        f32x4 acc1 = {0.f, 0.f, 0.f, 0.f};
        const short* b0p = wT + (size_t)(c * 16 + m) * H_F + quad * 8;
        const short* b1p = b0p + 16 * H_F;
        #pragma unroll
        for (int ks = 0; ks < 4; ks++) {
            short8 b0 = *(const short8*)(b0p + ks * 32);
            short8 b1 = *(const short8*)(b1p + ks * 32);
            acc0 = __builtin_amdgcn_mfma_f32_16x16x32_bf16(afrag[ks], b0, acc0, 0, 0, 0);
            acc1 = __builtin_amdgcn_mfma_f32_16x16x32_bf16(afrag[ks], b1, acc1, 0, 0, 0);
        }
        int col0 = c * 16 + m;
        int rbase = blockIdx.x * 64 + wave * 16 + quad * 4;
        float bg0 = b[col0], bg1 = b[col0 + 16];
        #pragma unroll
        for (int r = 0; r < 4; r++) {
            size_t idx = (size_t)(rbase + r) * C_F + col0;
            out[idx] = acc0[r] + bg0;
            out[idx + 16] = acc1[r] + bg1;
        }
    }
}

extern "C" void kernel_launch(void* const* d_in, const int* in_sizes, int n_in,
                              void* d_out, int out_size, void* d_ws, size_t ws_size,
                              hipStream_t stream) {
    const float* x     = (const float*)d_in[0];
    const float* fc1_w = (const float*)d_in[1];
    const float* fc1_b = (const float*)d_in[2];
    const float* W1    = (const float*)d_in[3];
    const float* W2    = (const float*)d_in[4];
    const float* bgc   = (const float*)d_in[5];
    const float* fc2_w = (const float*)d_in[6];
    const float* fc2_b = (const float*)d_in[7];
    const int*   src   = (const int*)d_in[8];
    const int*   dst   = (const int*)d_in[9];
    float* out = (float*)d_out;

    char* p = (char*)d_ws;
    auto alloc = [&](size_t bytes) {
        char* r = p;
        p += (bytes + 255) & ~(size_t)255;
        return r;
    };
    int*   cnt_out   = (int*)alloc((size_t)N_NODES * 4);
    int*   cnt_in    = (int*)alloc((size_t)N_NODES * 4);
    int*   row_ptr   = (int*)alloc((size_t)(N_NODES + 1) * 4);
    int*   row_local = (int*)alloc((size_t)N_NODES * 4);
    int*   blk_sum   = (int*)alloc((size_t)SCAN_BLKS * 4);
    int*   blk_off   = (int*)alloc((size_t)SCAN_BLKS * 4);
    unsigned short* pos16 = (unsigned short*)alloc((size_t)N_EDGES * 2);
    int*   col     = (int*)alloc((size_t)N_EDGES * 4);
    float* wv      = (float*)alloc((size_t)N_EDGES * 4);
    float* hA      = (float*)alloc((size_t)N_NODES * H_F * 4);
    float* hB      = (float*)alloc((size_t)N_NODES * H_F * 4);
    float* agg     = (float*)alloc((size_t)N_NODES * H_F * 4);
    unsigned short* h0b = (unsigned short*)alloc((size_t)N_NODES * H_F * 2);
    unsigned short* hAb = (unsigned short*)alloc((size_t)N_NODES * H_F * 2);
    unsigned short* hBb = (unsigned short*)alloc((size_t)N_NODES * H_F * 2);
    short* fc1_wT  = (short*)alloc((size_t)128 * 256 * 2);
    short* WcatT   = (short*)alloc((size_t)4 * 128 * 256 * 2);
    short* fc2_wT  = (short*)alloc((size_t)64 * 128 * 2);

    hipMemsetAsync(cnt_out, 0, (size_t)N_NODES * 4, stream);
    hipMemsetAsync(cnt_in,  0, (size_t)N_NODES * 4, stream);

    prep_w<<<512, 256, 0, stream>>>(fc1_w, W1, W2, fc2_w, fc1_wT, WcatT, fc2_wT);
    deg_fc1_fused<<<1250, 256, 0, stream>>>(src, dst, cnt_out, cnt_in, pos16,
                                            x, fc1_wT, fc1_b, h0b);
    scan1<<<SCAN_BLKS, 256, 0, stream>>>(cnt_in, row_local, blk_sum);
    scan2<<<1, 256, 0, stream>>>(blk_sum, blk_off);
    fill_fused<<<2500 + SCAN_BLKS, 256, 0, stream>>>(src, dst, pos16, cnt_out, cnt_in,
                                                     row_local, blk_off, col, wv, row_ptr);

    // layer schedule: identity source (fp32 after layer 0), dual-format outputs
    // l=0: id=h0b (bf16) -> hA + hAb
    // l=1: id=hA        -> hB + hBb
    // l=2: id=hB        -> hA + hAb
    // l=3: id=hA        -> (skip fp32) + hBb ; fc2 reads hBb
    const float* id_f[4]          = {nullptr, hA, hB, hA};
    const unsigned short* id_b    = h0b;
    const unsigned short* sp_in[4]= {h0b, hAb, hBb, hAb};
    float* out_f[4]               = {hA, hB, hA, nullptr};
    unsigned short* out_b[4]      = {hAb, hBb, hAb, hBb};

    for (int l = 0; l < L_LAYERS; l++) {
        float beta = (float)log(1.0 / (double)(l + 1) + 1.0);
        spmm_kernel<<<N_NODES / 4, 256, 0, stream>>>(sp_in[l], row_ptr, col, wv, agg);
        combine_mfma<<<N_NODES / 64, 256, 0, stream>>>(agg, h0b, id_f[l], id_b,
                                                       WcatT + (size_t)l * 128 * 256,
                                                       bgc + (size_t)l * H_F,
                                                       beta, out_f[l], out_b[l]);
    }
    fc2_mfma<<<N_NODES / 64, 256, 0, stream>>>(hBb, fc2_wT, fc2_b, out);
}